// Round 6
// baseline (484.924 us; speedup 1.0000x reference)
//
#include <hip/hip_runtime.h>
#include <hip/hip_bf16.h>
#include <cstdint>
#include <cstddef>

typedef __attribute__((ext_vector_type(8))) short short8;
typedef __attribute__((ext_vector_type(4))) float floatx4;

// V=1024 C=8 T=256 BP=4 K=512 E=128 D=128 NB=24 NH=4 HD=32 FF=512 R=8 B=32

__device__ __forceinline__ ushort f2bf(float f) {
    union { float f; unsigned int u; } x; x.f = f;
    unsigned int r = (x.u + 0x7fffu + ((x.u >> 16) & 1u)) >> 16;
    return (ushort)r;
}
__device__ __forceinline__ float bf2f(ushort u) {
    union { unsigned int u; float f; } x; x.u = ((unsigned int)u) << 16;
    return x.f;
}

// device-scope grid barrier (all blocks co-resident by construction)
__device__ __forceinline__ void gbar(unsigned int* bar, unsigned int nb) {
    __threadfence();
    __syncthreads();
    if (threadIdx.x == 0) {
        atomicAdd(bar, 1u);
        while (atomicAdd(bar, 0u) < nb) __builtin_amdgcn_s_sleep(2);
    }
    __syncthreads();
    __threadfence();
}

// ---------------- single merged prep kernel ----------------
__global__ __launch_bounds__(256) void prep_all(
    const float* __restrict__ emb, const float* __restrict__ w1,
    const float* __restrict__ w2, const float* __restrict__ cbi,
    const float* __restrict__ cbv, const float* __restrict__ aiw,
    const float* __restrict__ aow, const float* __restrict__ l1w,
    const float* __restrict__ l2w,
    ushort* __restrict__ ebf, ushort* __restrict__ w1bf, ushort* __restrict__ w2bf,
    float* __restrict__ cbiT, float* __restrict__ cbvT,
    ushort* __restrict__ aiwbf, ushort* __restrict__ aowbf,
    ushort* __restrict__ l1wbf, ushort* __restrict__ l2wbf,
    float* __restrict__ accum)
{
    int idx = blockIdx.x * 256 + threadIdx.x;
    if (idx < 16) accum[idx] = 0.f;     // losses + completion + barrier counters
    if (idx < 131072) {
        ebf[idx] = f2bf(emb[idx]);
    } else if (idx < 262144) {
        int j = idx - 131072; w2bf[j] = f2bf(w2[j]);
    } else if (idx < 327680) {
        int j = idx - 262144; cbiT[(j & 127) * 512 + (j >> 7)] = cbi[j];
    } else if (idx < 393216) {
        int j = idx - 327680; cbvT[(j & 127) * 512 + (j >> 7)] = cbv[j];
    } else if (idx < 442368) {
        int j = idx - 393216; aiwbf[j] = f2bf(aiw[j]);
    } else if (idx < 475136) {
        int j = idx - 442368; aowbf[j] = f2bf(aow[j]);
    } else if (idx < 540672) {
        int j = idx - 475136; l1wbf[j] = f2bf(l1w[j]);
    } else if (idx < 606208) {
        int j = idx - 540672; l2wbf[j] = f2bf(l2w[j]);
    } else if (idx < 2179072) {
        int j = idx - 606208;   // w1bf[kw][c][co][e] <- conv1_w[co][c*128+e][kw]
        int e  = j & 127;
        int co = (j >> 7) & 511;
        int cc = (j >> 16) & 7;
        int kw = j >> 19;
        w1bf[j] = f2bf(w1[(co * 1024 + cc * 128 + e) * 3 + kw]);
    }
}

// ---------------- U build: U[kc][v][co] = emb[v] . W1[kc][co] ----------------
__global__ __launch_bounds__(512) void ubuild_kernel(
    const ushort* __restrict__ ebf, const ushort* __restrict__ w1bf,
    ushort* __restrict__ U)
{
    constexpr int LDA = 136;
    __shared__ ushort As[128 * LDA];
    __shared__ ushort Bs[128 * LDA];
    const int tid = threadIdx.x;
    const int bx = blockIdx.x;               // 768 = 24 kc x 8 mt x 4 nt
    const int kc = bx >> 5, rem = bx & 31, mt = rem >> 2, nt = rem & 3;
    const int v0 = mt << 7, co0 = nt << 7;
    const int w = tid >> 6, lane = tid & 63;
    const int wm = w & 1, wn = w >> 1;
    const int rA = lane & 15, q4 = lane >> 4;
    const int ch = tid & 15, rowst = tid >> 4;

    for (int p = 0; p < 4; ++p) {
        const int row = p * 32 + rowst;
        *(uint4*)(As + row * LDA + ch * 8) =
            *(const uint4*)(ebf + (size_t)(v0 + row) * 128 + ch * 8);
        *(uint4*)(Bs + row * LDA + ch * 8) =
            *(const uint4*)(w1bf + (size_t)kc * 65536 + (size_t)(co0 + row) * 128 + ch * 8);
    }
    __syncthreads();

    floatx4 acc[4][2];
    for (int mi = 0; mi < 4; ++mi)
        for (int ni = 0; ni < 2; ++ni)
            acc[mi][ni] = (floatx4)(0.0f);
    for (int ks = 0; ks < 4; ++ks) {
        const int k0 = ks * 32 + q4 * 8;
        short8 a[4], bfr[2];
        for (int mi = 0; mi < 4; ++mi)
            a[mi] = *(const short8*)(As + (wm * 64 + mi * 16 + rA) * LDA + k0);
        for (int ni = 0; ni < 2; ++ni)
            bfr[ni] = *(const short8*)(Bs + (wn * 32 + ni * 16 + rA) * LDA + k0);
        for (int mi = 0; mi < 4; ++mi)
            for (int ni = 0; ni < 2; ++ni)
                acc[mi][ni] = __builtin_amdgcn_mfma_f32_16x16x32_bf16(
                    a[mi], bfr[ni], acc[mi][ni], 0, 0, 0);
    }
    for (int ni = 0; ni < 2; ++ni) {
        const int col = co0 + wn * 32 + ni * 16 + rA;
        for (int mi = 0; mi < 4; ++mi)
            for (int r = 0; r < 4; ++r) {
                const int row = v0 + wm * 64 + mi * 16 + q4 * 4 + r;
                U[((size_t)kc * 1024 + row) * 512 + col] = f2bf(acc[mi][ni][r]);
            }
    }
}

// ---------------- conv1 via gather-accumulate over U ----------------
__global__ __launch_bounds__(256) void conv1_gather(
    const int* __restrict__ tp, const int* __restrict__ tcu, const int* __restrict__ tn,
    const ushort* __restrict__ U, const float* __restrict__ b1,
    ushort* __restrict__ y1)
{
    __shared__ int tokL[34 * 8];
    const int bx = blockIdx.x;
    const int set = bx >> 8, bb = (bx >> 3) & 31, pp = bx & 7;
    const int t0 = pp << 5;
    const int* tok = (set == 0) ? tp : ((set == 1) ? tcu : tn);
    const int tid = threadIdx.x;
    const int w = tid >> 6, lane = tid & 63;

    for (int idx = tid; idx < 272; idx += 256) {
        const int row = idx >> 3, cc = idx & 7;
        const int gt = t0 + row - 1;
        tokL[idx] = (gt >= 0 && gt < 256) ? tok[bb * 2048 + gt * 8 + cc] : -1;
    }
    float bias[8];
    {
        const float4* b4 = (const float4*)(b1 + lane * 8);
        float4 x = b4[0], y = b4[1];
        bias[0] = x.x; bias[1] = x.y; bias[2] = x.z; bias[3] = x.w;
        bias[4] = y.x; bias[5] = y.y; bias[6] = y.z; bias[7] = y.w;
    }
    __syncthreads();

    const size_t outbase = ((size_t)(set * 32 + bb) * 256 + t0) * 512 + lane * 8;
    for (int tl = 0; tl < 8; ++tl) {
        const int row = w * 8 + tl;
        float acc[8];
        for (int j = 0; j < 8; ++j) acc[j] = bias[j];
        for (int kw = 0; kw < 3; ++kw) {
            const int* trow = tokL + (row + kw) * 8;
            for (int cc = 0; cc < 8; ++cc) {
                const int u = trow[cc];
                if (u >= 0) {
                    const short8 s = *(const short8*)(U + (((size_t)(kw * 8 + cc) * 1024 + u) * 512 + lane * 8));
                    for (int j = 0; j < 8; ++j) acc[j] += bf2f((ushort)s[j]);
                }
            }
        }
        ushort o[8];
        for (int j = 0; j < 8; ++j) {
            float v = acc[j];
            o[j] = f2bf(v > 0.f ? v : 0.f);
        }
        *(uint4*)(y1 + outbase + (size_t)row * 512) = *(const uint4*)o;
    }
}

// ---------------- conv1: implicit GEMM fallback (small-ws path) ----------------
__global__ __launch_bounds__(512, 4) void conv1_mfma(
    const int* __restrict__ tp, const int* __restrict__ tcu, const int* __restrict__ tn,
    const ushort* __restrict__ ebf, const ushort* __restrict__ w1bf,
    const float* __restrict__ b1, ushort* __restrict__ y1)
{
    constexpr int LDA = 136;
    __shared__ ushort As[130 * LDA];
    __shared__ ushort Bs[128 * LDA];
    __shared__ int tokL[130 * 8];
    const int tid = threadIdx.x;
    const int bx = blockIdx.x;
    const int nb = bx & 3, mb = bx >> 2;
    const int set = mb >> 6, rem = mb & 63, bb = rem >> 1, t0 = (rem & 1) << 7;
    const int n0 = nb << 7;
    const int* tok = (set == 0) ? tp : ((set == 1) ? tcu : tn);

    for (int idx = tid; idx < 1040; idx += 512) {
        const int row = idx >> 3, cc = idx & 7;
        const int gt = t0 + row - 1;
        tokL[idx] = (gt >= 0 && gt < 256) ? tok[bb * 2048 + gt * 8 + cc] : -1;
    }

    const int w = tid >> 6, lane = tid & 63;
    const int wm = w & 1, wn = w >> 1;
    const int rA = lane & 15, q4 = lane >> 4;
    const int ch = tid & 15, rowst = tid >> 4;

    floatx4 acc[4][2];
    for (int mi = 0; mi < 4; ++mi)
        for (int ni = 0; ni < 2; ++ni)
            acc[mi][ni] = (floatx4)(0.0f);

    __syncthreads();

    for (int cc = 0; cc < 8; ++cc) {
        for (int p = 0; p < 5; ++p) {
            const int row = p * 32 + rowst;
            if (row < 130) {
                const int tk = tokL[row * 8 + cc];
                uint4 val = make_uint4(0u, 0u, 0u, 0u);
                if (tk >= 0) val = *(const uint4*)(ebf + tk * 128 + ch * 8);
                *(uint4*)(As + row * LDA + ch * 8) = val;
            }
        }
        for (int kw = 0; kw < 3; ++kw) {
            const ushort* wsrc = w1bf + ((size_t)((kw * 8 + cc) * 512 + n0)) * 128;
            for (int p = 0; p < 4; ++p) {
                const int row = p * 32 + rowst;
                *(uint4*)(Bs + row * LDA + ch * 8) = *(const uint4*)(wsrc + row * 128 + ch * 8);
            }
            __syncthreads();
            for (int ks = 0; ks < 4; ++ks) {
                const int k0 = ks * 32 + q4 * 8;
                short8 a[4], bfr[2];
                for (int mi = 0; mi < 4; ++mi)
                    a[mi] = *(const short8*)(As + (wm * 64 + mi * 16 + rA + kw) * LDA + k0);
                for (int ni = 0; ni < 2; ++ni)
                    bfr[ni] = *(const short8*)(Bs + (wn * 32 + ni * 16 + rA) * LDA + k0);
                for (int mi = 0; mi < 4; ++mi)
                    for (int ni = 0; ni < 2; ++ni)
                        acc[mi][ni] = __builtin_amdgcn_mfma_f32_16x16x32_bf16(
                            a[mi], bfr[ni], acc[mi][ni], 0, 0, 0);
            }
            __syncthreads();
        }
    }
    for (int ni = 0; ni < 2; ++ni) {
        const int co = n0 + wn * 32 + ni * 16 + rA;
        const float bias = b1[co];
        for (int mi = 0; mi < 4; ++mi) {
            for (int r = 0; r < 4; ++r) {
                const int t = t0 + wm * 64 + mi * 16 + q4 * 4 + r;
                float v = acc[mi][ni][r] + bias;
                v = v > 0.f ? v : 0.f;
                y1[((size_t)(set * 32 + bb) * 256 + t) * 512 + co] = f2bf(v);
            }
        }
    }
}

// ---------------- conv2 + avgpool(64): 128x128 tile ----------------
__global__ __launch_bounds__(512, 4) void conv2_mfma(
    const ushort* __restrict__ y1, const ushort* __restrict__ w2bf,
    const float* __restrict__ b2, float* __restrict__ y2)
{
    constexpr int LDA = 136;
    __shared__ ushort As[128 * LDA];
    __shared__ ushort Bs[128 * LDA];
    __shared__ float pool[256];
    const int tid = threadIdx.x;
    const int bx = blockIdx.x;
    const int nb = bx & 1, mb = bx >> 1;
    const int set = mb >> 6, rem = mb & 63, bb = rem >> 1, t0 = (rem & 1) << 7;
    const int n0 = nb << 7;
    const int w = tid >> 6, lane = tid & 63;
    const int wm = w & 1, wn = w >> 1;
    const int rA = lane & 15, q4 = lane >> 4;
    const int ch = tid & 15, rowst = tid >> 4;

    floatx4 acc[4][2];
    for (int mi = 0; mi < 4; ++mi)
        for (int ni = 0; ni < 2; ++ni)
            acc[mi][ni] = (floatx4)(0.0f);

    const size_t arowbase = ((size_t)(set * 32 + bb) * 256 + t0) * 512;
    for (int kc = 0; kc < 4; ++kc) {
        for (int p = 0; p < 4; ++p) {
            const int row = p * 32 + rowst;
            *(uint4*)(As + row * LDA + ch * 8) =
                *(const uint4*)(y1 + arowbase + (size_t)row * 512 + kc * 128 + ch * 8);
            *(uint4*)(Bs + row * LDA + ch * 8) =
                *(const uint4*)(w2bf + (size_t)(n0 + row) * 512 + kc * 128 + ch * 8);
        }
        __syncthreads();
        for (int ks = 0; ks < 4; ++ks) {
            const int k0 = ks * 32 + q4 * 8;
            short8 a[4], bfr[2];
            for (int mi = 0; mi < 4; ++mi)
                a[mi] = *(const short8*)(As + (wm * 64 + mi * 16 + rA) * LDA + k0);
            for (int ni = 0; ni < 2; ++ni)
                bfr[ni] = *(const short8*)(Bs + (wn * 32 + ni * 16 + rA) * LDA + k0);
            for (int mi = 0; mi < 4; ++mi)
                for (int ni = 0; ni < 2; ++ni)
                    acc[mi][ni] = __builtin_amdgcn_mfma_f32_16x16x32_bf16(
                        a[mi], bfr[ni], acc[mi][ni], 0, 0, 0);
        }
        __syncthreads();
    }
    for (int ni = 0; ni < 2; ++ni) {
        const int col = wn * 32 + ni * 16 + rA;
        const float bias = b2[n0 + col];
        float s = 0.f;
        for (int mi = 0; mi < 4; ++mi)
            for (int r = 0; r < 4; ++r) {
                float v = acc[mi][ni][r] + bias;
                s += v > 0.f ? v : 0.f;
            }
        s += __shfl_xor(s, 16);
        s += __shfl_xor(s, 32);
        if (q4 == 0) pool[wm * 128 + col] = s;
    }
    __syncthreads();
    if (tid < 256) {
        const int wrow = tid >> 7, col = tid & 127;
        const int p = (t0 >> 6) + wrow;
        y2[((size_t)(set * 32 + bb) * 4 + p) * 256 + n0 + col] = pool[tid] * (1.f / 64.f);
    }
}

// ---------------- VQ ----------------
__global__ __launch_bounds__(256) void vq_kernel(
    const float* __restrict__ y2, const float* __restrict__ cbiT, const float* __restrict__ cbvT,
    const float* __restrict__ cbi, const float* __restrict__ cbv,
    const float* __restrict__ pos, float* __restrict__ ztr, ushort* __restrict__ xbf,
    float* __restrict__ accum)
{
    const int q = blockIdx.x;
    const int tid = threadIdx.x;
    const int set = q >> 7, bb = (q >> 2) & 31, p = q & 3;
    __shared__ float zloc[256];
    __shared__ float bestv[4];
    __shared__ int   besti[4];
    __shared__ int   code_sh[2];
    __shared__ float wsum2[4];
    zloc[tid] = y2[(size_t)q * 256 + tid];
    __syncthreads();
    const int w = tid >> 6, lane = tid & 63;
    const int half = w >> 1, sub = w & 1;
    const float4* cbT4 = (const float4*)(half ? cbvT : cbiT);
    const float* zh = zloc + half * 128;
    const int k4 = sub * 64 + lane;
    float a0 = 0.f, a1 = 0.f, a2 = 0.f, a3 = 0.f;
    for (int d = 0; d < 128; ++d) {
        float4 v = cbT4[d * 128 + k4];
        const float z = zh[d];
        float d0 = z - v.x, d1 = z - v.y, d2 = z - v.z, d3 = z - v.w;
        a0 += d0 * d0; a1 += d1 * d1; a2 += d2 * d2; a3 += d3 * d3;
    }
    float best = a0; int bidx = k4 * 4;
    if (a1 < best) { best = a1; bidx = k4 * 4 + 1; }
    if (a2 < best) { best = a2; bidx = k4 * 4 + 2; }
    if (a3 < best) { best = a3; bidx = k4 * 4 + 3; }
    for (int off = 32; off > 0; off >>= 1) {
        float ov = __shfl_xor(best, off);
        int   oi = __shfl_xor(bidx, off);
        if (ov < best || (ov == best && oi < bidx)) { best = ov; bidx = oi; }
    }
    if (lane == 0) { bestv[w] = best; besti[w] = bidx; }
    __syncthreads();
    if (tid < 2) {
        float v0 = bestv[tid * 2], v1 = bestv[tid * 2 + 1];
        int   i0 = besti[tid * 2], i1 = besti[tid * 2 + 1];
        code_sh[tid] = (v1 < v0 || (v1 == v0 && i1 < i0)) ? i1 : i0;
    }
    __syncthreads();
    const int hh = tid >> 7, d = tid & 127;
    const int code = code_sh[hh];
    const float* cb = hh ? cbv : cbi;
    const float zq = cb[code * 128 + d];
    const float diff = zloc[hh * 128 + d] - zq;
    float sq = diff * diff;
    for (int off = 32; off > 0; off >>= 1) sq += __shfl_xor(sq, off);
    if (lane == 0) wsum2[w] = sq;
    const int s = (set * 2 + hh) * 4 + p;
    const float val = zq + pos[s * 128 + d];
    ztr[((size_t)bb * 24 + s) * 128 + d] = val;
    xbf[((size_t)bb * 24 + s) * 128 + d] = f2bf(val);
    __syncthreads();
    if (tid == 0) atomicAdd(&accum[0], wsum2[0] + wsum2[1] + wsum2[2] + wsum2[3]);
}

// ---------------- persistent-grid transformer tail, device helpers ----------------
__device__ void gemm64_dev(const ushort* __restrict__ A, const ushort* __restrict__ Bw,
                           const float* __restrict__ bias, float* Cof, ushort* Cobf,
                           int KTOT, int NTOT, bool relu, int mblk, int nblk, char* SMEM)
{
    ushort* As = (ushort*)SMEM;
    ushort* Bs = (ushort*)(SMEM + 17408);
    const int tid = threadIdx.x;
    const int m0 = mblk * 64, n0 = nblk * 64;
    const int w = tid >> 6, lane = tid & 63;
    const int rA = lane & 15, q4 = lane >> 4;
    const int ch = tid & 15, rowst = tid >> 4;
    floatx4 acc[4];
    for (int mi = 0; mi < 4; ++mi) acc[mi] = (floatx4)(0.f);
    for (int kc = 0; kc < KTOT / 128; ++kc) {
        for (int i = 0; i < 4; ++i) {
            const int row = i * 16 + rowst;
            *(uint4*)(As + row * 136 + ch * 8) =
                *(const uint4*)(A + (size_t)(m0 + row) * KTOT + kc * 128 + ch * 8);
            *(uint4*)(Bs + row * 136 + ch * 8) =
                *(const uint4*)(Bw + (size_t)(n0 + row) * KTOT + kc * 128 + ch * 8);
        }
        __syncthreads();
        for (int ks = 0; ks < 4; ++ks) {
            const int k0 = ks * 32 + q4 * 8;
            short8 bfr = *(const short8*)(Bs + (w * 16 + rA) * 136 + k0);
            for (int mi = 0; mi < 4; ++mi) {
                short8 a = *(const short8*)(As + (mi * 16 + rA) * 136 + k0);
                acc[mi] = __builtin_amdgcn_mfma_f32_16x16x32_bf16(a, bfr, acc[mi], 0, 0, 0);
            }
        }
        __syncthreads();
    }
    const int col = n0 + w * 16 + rA;
    const float bs = bias[col];
    for (int mi = 0; mi < 4; ++mi)
        for (int r = 0; r < 4; ++r) {
            const int row = m0 + mi * 16 + q4 * 4 + r;
            float vv = acc[mi][r] + bs;
            if (relu) vv = vv > 0.f ? vv : 0.f;
            if (Cobf) Cobf[(size_t)row * NTOT + col] = f2bf(vv);
            else      Cof[(size_t)row * NTOT + col]  = vv;
        }
}

__device__ void gemm_ln_dev(const ushort* __restrict__ A, const ushort* __restrict__ Bw,
                            const float* __restrict__ bias, const float* __restrict__ resid,
                            const float* __restrict__ g, const float* __restrict__ beta,
                            ushort* outbf, float* outf, int KTOT, int mblk, char* SMEM)
{
    ushort* As  = (ushort*)SMEM;                 // 64 x 136
    ushort* Bs  = (ushort*)(SMEM + 17408);       // 128 x 136
    float*  ps  = (float*)(SMEM + 52224);
    float*  pq  = (float*)(SMEM + 53248);
    float*  muv = (float*)(SMEM + 54272);
    float*  inv = (float*)(SMEM + 54528);
    const int tid = threadIdx.x;
    const int m0 = mblk * 64;
    const int w = tid >> 6, lane = tid & 63;
    const int rA = lane & 15, q4 = lane >> 4;
    const int ch = tid & 15, rowst = tid >> 4;

    floatx4 acc[4][2];
    for (int mi = 0; mi < 4; ++mi)
        for (int ni = 0; ni < 2; ++ni)
            acc[mi][ni] = (floatx4)(0.f);

    for (int kc = 0; kc < KTOT / 128; ++kc) {
        for (int i = 0; i < 4; ++i) {
            const int row = i * 16 + rowst;
            *(uint4*)(As + row * 136 + ch * 8) =
                *(const uint4*)(A + (size_t)(m0 + row) * KTOT + kc * 128 + ch * 8);
        }
        for (int i = 0; i < 8; ++i) {
            const int row = i * 16 + rowst;
            *(uint4*)(Bs + row * 136 + ch * 8) =
                *(const uint4*)(Bw + (size_t)row * KTOT + kc * 128 + ch * 8);
        }
        __syncthreads();
        for (int ks = 0; ks < 4; ++ks) {
            const int k0 = ks * 32 + q4 * 8;
            short8 a[4], bfr[2];
            for (int mi = 0; mi < 4; ++mi)
                a[mi] = *(const short8*)(As + (mi * 16 + rA) * 136 + k0);
            for (int ni = 0; ni < 2; ++ni)
                bfr[ni] = *(const short8*)(Bs + ((w * 2 + ni) * 16 + rA) * 136 + k0);
            for (int mi = 0; mi < 4; ++mi)
                for (int ni = 0; ni < 2; ++ni)
                    acc[mi][ni] = __builtin_amdgcn_mfma_f32_16x16x32_bf16(
                        a[mi], bfr[ni], acc[mi][ni], 0, 0, 0);
        }
        __syncthreads();
    }
    for (int ni = 0; ni < 2; ++ni) {
        const int col = (w * 2 + ni) * 16 + rA;
        const float bs = bias[col];
        for (int mi = 0; mi < 4; ++mi)
            for (int r = 0; r < 4; ++r) {
                const int row = m0 + mi * 16 + q4 * 4 + r;
                acc[mi][ni][r] += bs + resid[(size_t)row * 128 + col];
            }
    }
    for (int mi = 0; mi < 4; ++mi)
        for (int r = 0; r < 4; ++r) {
            float s  = acc[mi][0][r] + acc[mi][1][r];
            float sq = acc[mi][0][r] * acc[mi][0][r] + acc[mi][1][r] * acc[mi][1][r];
            for (int off = 1; off < 16; off <<= 1) {
                s  += __shfl_xor(s, off);
                sq += __shfl_xor(sq, off);
            }
            if (rA == 0) {
                const int rl = mi * 16 + q4 * 4 + r;
                ps[rl * 4 + w] = s;
                pq[rl * 4 + w] = sq;
            }
        }
    __syncthreads();
    if (tid < 64) {
        float s  = ps[tid * 4] + ps[tid * 4 + 1] + ps[tid * 4 + 2] + ps[tid * 4 + 3];
        float sq = pq[tid * 4] + pq[tid * 4 + 1] + pq[tid * 4 + 2] + pq[tid * 4 + 3];
        float mu = s * (1.f / 128.f);
        float var = sq * (1.f / 128.f) - mu * mu;
        muv[tid] = mu;
        inv[tid] = rsqrtf(var + 1e-5f);
    }
    __syncthreads();
    for (int ni = 0; ni < 2; ++ni) {
        const int col = (w * 2 + ni) * 16 + rA;
        const float gg = g[col], bb = beta[col];
        for (int mi = 0; mi < 4; ++mi)
            for (int r = 0; r < 4; ++r) {
                const int rl = mi * 16 + q4 * 4 + r;
                const int row = m0 + rl;
                float v = (acc[mi][ni][r] - muv[rl]) * inv[rl] * gg + bb;
                if (outbf) outbf[(size_t)row * 128 + col] = f2bf(v);
                if (outf)  outf[(size_t)row * 128 + col]  = v;
            }
    }
}

// ---------------- persistent tail: 96 blocks, 6 phases, 5 grid barriers ----------------
__global__ __launch_bounds__(256) void tail_pk(
    const ushort* __restrict__ xbf, const float* __restrict__ ztr,
    const ushort* __restrict__ aiwbf, const float* __restrict__ aib,
    const ushort* __restrict__ aowbf, const float* __restrict__ aob,
    const float* __restrict__ g1, const float* __restrict__ be1,
    const ushort* __restrict__ l1wbf, const float* __restrict__ l1b,
    const ushort* __restrict__ l2wbf, const float* __restrict__ l2b,
    const float* __restrict__ g2, const float* __restrict__ be2,
    const float* __restrict__ lora_a,
    float* __restrict__ QKV, ushort* __restrict__ obuf,
    ushort* __restrict__ x1bf, float* __restrict__ x1f,
    ushort* __restrict__ hff, float* __restrict__ zf,
    float* __restrict__ hbuf, unsigned int* __restrict__ bar)
{
    __shared__ __align__(16) char SM[55296];
    const unsigned int NB = 96;
    const int bx = blockIdx.x;
    const int tid = threadIdx.x;

    // P0: qkv = X @ aiw^T + aib   (768x384, K=128)
    if (bx < 72) gemm64_dev(xbf, aiwbf, aib, QKV, nullptr, 128, 384, false, bx / 6, bx % 6, SM);
    gbar(bar + 0, NB);

    // P1: attention — block = batch, wave = head
    if (bx < 32) {
        const int b = bx;
        const int w = tid >> 6, lane = tid & 63;
        float* F = (float*)SM + w * 2880;
        float* q = F; float* k = F + 768; float* v = F + 1536; float* sc = F + 2304;
        for (int l = 0; l < 12; ++l) {
            const int idx = l * 64 + lane;
            const int s = idx >> 5, d = idx & 31;
            const size_t base = ((size_t)(b * 24 + s)) * 384 + w * 32 + d;
            q[idx] = QKV[base];
            k[idx] = QKV[base + 128];
            v[idx] = QKV[base + 256];
        }
        __syncthreads();
        for (int l = 0; l < 9; ++l) {
            const int e = l * 64 + lane;
            const int i = e / 24, j = e - i * 24;
            float s = 0.f;
            for (int d = 0; d < 32; ++d) s += q[i * 32 + d] * k[j * 32 + d];
            sc[i * 24 + j] = s * 0.17677669529663687f;
        }
        __syncthreads();
        if (lane < 24) {
            float* row = sc + lane * 24;
            float m = row[0];
            for (int j = 1; j < 24; ++j) m = row[j] > m ? row[j] : m;
            float ssum = 0.f;
            for (int j = 0; j < 24; ++j) { float e = __expf(row[j] - m); row[j] = e; ssum += e; }
            float iv = 1.f / ssum;
            for (int j = 0; j < 24; ++j) row[j] *= iv;
        }
        __syncthreads();
        for (int l = 0; l < 12; ++l) {
            const int idx = l * 64 + lane;
            const int s = idx >> 5, d = idx & 31;
            float a = 0.f;
            for (int j = 0; j < 24; ++j) a += sc[s * 24 + j] * v[j * 32 + d];
            obuf[((size_t)(b * 24 + s)) * 128 + w * 32 + d] = f2bf(a);
        }
    }
    gbar(bar + 1, NB);

    // P2: proj + resid + LN1  (768x128, K=128)
    if (bx < 12) gemm_ln_dev(obuf, aowbf, aob, ztr, g1, be1, x1bf, x1f, 128, bx, SM);
    gbar(bar + 2, NB);

    // P3: ff1 + relu  (768x512, K=128)
    if (bx < 96) gemm64_dev(x1bf, l1wbf, l1b, nullptr, hff, 128, 512, true, bx / 8, bx % 8, SM);
    gbar(bar + 3, NB);

    // P4: ff2 + resid + LN2  (768x128, K=512) -> zf (f32)
    if (bx < 12) gemm_ln_dev(hff, l2wbf, l2b, x1f, g2, be2, nullptr, zf, 512, bx, SM);
    gbar(bar + 4, NB);

    // P5: lora_a — block = batch
    if (bx < 32) {
        float* zl = (float*)SM;
        for (int i = tid; i < 3072; i += 256) zl[i] = zf[(size_t)bx * 3072 + i];
        __syncthreads();
        const int w = tid >> 6, lane = tid & 63;
        for (int rr = 0; rr < 2; ++rr) {
            const int r = w + rr * 4;
            float a = 0.f;
            for (int i = lane; i < 3072; i += 64)
                a += lora_a[(size_t)r * 3072 + i] * zl[i];
            for (int off = 32; off > 0; off >>= 1) a += __shfl_xor(a, off);
            if (lane == 0) hbuf[bx * 8 + r] = a;
        }
    }
}

// ---------------- logits + log-softmax + NLL + fused finalize ----------------
__global__ __launch_bounds__(256) void logits_kernel(
    const float* __restrict__ hbuf, const float* __restrict__ lora_b,
    const int* __restrict__ tokc, float* __restrict__ accum, float* __restrict__ out)
{
    const int tid = threadIdx.x;
    const int tcb = blockIdx.x;
    __shared__ float hl[256];
    __shared__ float wsum[4];
    __shared__ float ltok;
    hl[tid] = hbuf[tid];
    float wr[4][8];
    for (int i = 0; i < 4; ++i) {
        const float4* pw = (const float4*)(lora_b + ((size_t)tcb * 1024 + tid + 256 * i) * 8);
        float4 x = pw[0], y = pw[1];
        wr[i][0] = x.x; wr[i][1] = x.y; wr[i][2] = x.z; wr[i][3] = x.w;
        wr[i][4] = y.x; wr[i][5] = y.y; wr[i][6] = y.z; wr[i][7] = y.w;
    }
    __syncthreads();
    float nll = 0.f;
    for (int bb = 0; bb < 32; ++bb) {
        const int tv = tokc[bb * 2048 + tcb];
        const float* h = hl + bb * 8;
        float h0 = h[0], h1 = h[1], h2 = h[2], h3 = h[3];
        float h4 = h[4], h5 = h[5], h6 = h[6], h7 = h[7];
        float sl = 0.f;
        for (int i = 0; i < 4; ++i) {
            float lg = h0 * wr[i][0] + h1 * wr[i][1] + h2 * wr[i][2] + h3 * wr[i][3]
                     + h4 * wr[i][4] + h5 * wr[i][5] + h6 * wr[i][6] + h7 * wr[i][7];
            sl += __expf(lg);
            if (tid + 256 * i == tv) ltok = lg;
        }
        for (int off = 32; off > 0; off >>= 1) sl += __shfl_xor(sl, off);
        if ((tid & 63) == 0) wsum[tid >> 6] = sl;
        __syncthreads();
        if (tid == 0) nll += logf(wsum[0] + wsum[1] + wsum[2] + wsum[3]) - ltok;
        __syncthreads();
    }
    if (tid == 0) {
        atomicAdd(&accum[1], nll);
        __threadfence();
        unsigned int prev = atomicAdd((unsigned int*)(accum + 2), 1u);
        if (prev == 2047u) {
            float vq  = atomicAdd(&accum[0], 0.f);
            float rec = atomicAdd(&accum[1], 0.f);
            out[0] = rec * (1.f / 65536.f) + 0.05f * vq * (1.f / 16384.f);
        }
    }
}

// ---------------- host ----------------
extern "C" void kernel_launch(void* const* d_in, const int* in_sizes, int n_in,
                              void* d_out, int out_size, void* d_ws, size_t ws_size,
                              hipStream_t stream) {
    const int*   tp   = (const int*)d_in[0];
    const int*   tcu  = (const int*)d_in[1];
    const int*   tn   = (const int*)d_in[2];
    const float* emb  = (const float*)d_in[3];
    const float* w1   = (const float*)d_in[4];
    const float* b1   = (const float*)d_in[5];
    const float* w2   = (const float*)d_in[6];
    const float* b2   = (const float*)d_in[7];
    const float* cbi  = (const float*)d_in[8];
    const float* cbv  = (const float*)d_in[9];
    const float* pos  = (const float*)d_in[10];
    const float* aiw  = (const float*)d_in[11];
    const float* aib  = (const float*)d_in[12];
    const float* aow  = (const float*)d_in[13];
    const float* aob  = (const float*)d_in[14];
    const float* g1   = (const float*)d_in[15];
    const float* be1  = (const float*)d_in[16];
    const float* l1w  = (const float*)d_in[17];
    const float* l1b  = (const float*)d_in[18];
    const float* l2w  = (const float*)d_in[19];
    const float* l2b  = (const float*)d_in[20];
    const float* g2   = (const float*)d_in[21];
    const float* be2  = (const float*)d_in[22];
    const float* lra  = (const float*)d_in[23];
    const float* lrb  = (const float*)d_in[24];

    char* wsb = (char*)d_ws;
    ushort* ebf  = (ushort*)(wsb + 0);            // 262144 B
    ushort* w1bf = (ushort*)(wsb + 262144);       // 3145728 B
    ushort* w2bf = (ushort*)(wsb + 3407872);      // 262144 B
    float*  cbiT = (float*)(wsb + 3670016);       // 262144 B
    float*  cbvT = (float*)(wsb + 3932160);       // 262144 B
    ushort* y1   = (ushort*)(wsb + 4194304);      // 25165824 B (dead after conv2)
    float*  y2   = (float*)(wsb + 29360128);      // 393216 B
    float*  ztr  = (float*)(wsb + 29753344);      // 393216 B
    float*  hbuf = (float*)(wsb + 30146560);      // 1024 B
    float*  accum= (float*)(wsb + 30147584);      // 64 B (losses + counter + barriers)
    ushort* aiwbf= (ushort*)(wsb + 30147648);     // 98304 B
    ushort* aowbf= (ushort*)(wsb + 30245952);     // 32768 B
    ushort* l1wbf= (ushort*)(wsb + 30278720);     // 131072 B
    ushort* l2wbf= (ushort*)(wsb + 30409792);     // 131072 B -> 30540864
    ushort* U    = (ushort*)(wsb + 30541824);     // 25165824 B -> 55707648 (optional)
    if (ws_size < 30540864) return;
    const bool use_u = (ws_size >= 55707648);

    // transformer temporaries alias the (dead-by-then) y1 region
    float*  QKV  = (float*)(wsb + 4194304);       // 1179648 B
    ushort* obuf = (ushort*)(wsb + 5373952);      // 196608 B
    ushort* x1bf = (ushort*)(wsb + 5570560);      // 196608 B
    float*  x1f  = (float*)(wsb + 5767168);       // 393216 B
    ushort* hff  = (ushort*)(wsb + 6160384);      // 786432 B
    float*  zf   = (float*)(wsb + 6946816);       // 393216 B
    ushort* xbf  = (ushort*)(wsb + 7340032);      // 196608 B

    prep_all<<<8512, 256, 0, stream>>>(emb, w1, w2, cbi, cbv, aiw, aow, l1w, l2w,
                                       ebf, w1bf, w2bf, cbiT, cbvT,
                                       aiwbf, aowbf, l1wbf, l2wbf, accum);
    if (use_u) {
        ubuild_kernel<<<768, 512, 0, stream>>>(ebf, w1bf, U);
        conv1_gather<<<768, 256, 0, stream>>>(tp, tcu, tn, U, b1, y1);
    } else {
        conv1_mfma<<<768, 512, 0, stream>>>(tp, tcu, tn, ebf, w1bf, b1, y1);
    }
    conv2_mfma<<<384, 512, 0, stream>>>(y1, w2bf, b2, y2);
    vq_kernel<<<384, 256, 0, stream>>>(y2, cbiT, cbvT, cbi, cbv, pos, ztr, xbf, accum);
    tail_pk<<<96, 256, 0, stream>>>(xbf, ztr, aiwbf, aib, aowbf, aob, g1, be1,
                                    l1wbf, l1b, l2wbf, l2b, g2, be2, lra,
                                    QKV, obuf, x1bf, x1f, hff, zf, hbuf,
                                    (unsigned int*)(accum + 4));
    logits_kernel<<<2048, 256, 0, stream>>>(hbuf, lrb, tcu, accum, (float*)d_out);
}

// Round 7
// 429.596 us; speedup vs baseline: 1.1288x; 1.1288x over previous
//
#include <hip/hip_runtime.h>
#include <hip/hip_bf16.h>
#include <cstdint>
#include <cstddef>

typedef __attribute__((ext_vector_type(8))) short short8;
typedef __attribute__((ext_vector_type(4))) float floatx4;

// V=1024 C=8 T=256 BP=4 K=512 E=128 D=128 NB=24 NH=4 HD=32 FF=512 R=8 B=32

__device__ __forceinline__ ushort f2bf(float f) {
    union { float f; unsigned int u; } x; x.f = f;
    unsigned int r = (x.u + 0x7fffu + ((x.u >> 16) & 1u)) >> 16;
    return (ushort)r;
}
__device__ __forceinline__ float bf2f(ushort u) {
    union { unsigned int u; float f; } x; x.u = ((unsigned int)u) << 16;
    return x.f;
}

// ---------------- single merged prep kernel ----------------
__global__ __launch_bounds__(256) void prep_all(
    const float* __restrict__ emb, const float* __restrict__ w1,
    const float* __restrict__ w2, const float* __restrict__ cbi,
    const float* __restrict__ cbv, const float* __restrict__ aiw,
    const float* __restrict__ aow, const float* __restrict__ l1w,
    const float* __restrict__ l2w,
    ushort* __restrict__ ebf, ushort* __restrict__ w1bf, ushort* __restrict__ w2bf,
    float* __restrict__ cbiT, float* __restrict__ cbvT,
    ushort* __restrict__ aiwbf, ushort* __restrict__ aowbf,
    ushort* __restrict__ l1wbf, ushort* __restrict__ l2wbf,
    float* __restrict__ accum)
{
    int idx = blockIdx.x * 256 + threadIdx.x;
    if (idx < 16) accum[idx] = 0.f;
    if (idx < 131072) {
        ebf[idx] = f2bf(emb[idx]);
    } else if (idx < 262144) {
        int j = idx - 131072; w2bf[j] = f2bf(w2[j]);
    } else if (idx < 327680) {
        int j = idx - 262144; cbiT[(j & 127) * 512 + (j >> 7)] = cbi[j];
    } else if (idx < 393216) {
        int j = idx - 327680; cbvT[(j & 127) * 512 + (j >> 7)] = cbv[j];
    } else if (idx < 442368) {
        int j = idx - 393216; aiwbf[j] = f2bf(aiw[j]);
    } else if (idx < 475136) {
        int j = idx - 442368; aowbf[j] = f2bf(aow[j]);
    } else if (idx < 540672) {
        int j = idx - 475136; l1wbf[j] = f2bf(l1w[j]);
    } else if (idx < 606208) {
        int j = idx - 540672; l2wbf[j] = f2bf(l2w[j]);
    } else if (idx < 1130496) {
        // coalesced w1 transpose: thread handles all 3 kw of one (co,cc,e)
        int j = idx - 606208;            // j = (co*8 + cc)*128 + e ... decode:
        int e  = j & 127;
        int cc = (j >> 7) & 7;
        int co = j >> 10;
        const float* src = w1 + ((size_t)co * 1024 + cc * 128 + e) * 3;
        float v0 = src[0], v1 = src[1], v2 = src[2];
        w1bf[((size_t)(0 * 8 + cc) * 512 + co) * 128 + e] = f2bf(v0);
        w1bf[((size_t)(1 * 8 + cc) * 512 + co) * 128 + e] = f2bf(v1);
        w1bf[((size_t)(2 * 8 + cc) * 512 + co) * 128 + e] = f2bf(v2);
    }
}

// ---------------- conv1: implicit GEMM, 256x128 tile (full sequence per block) ----------------
// grid 384 = 96 (set,b) x 4 n-tiles; 512 threads = 8 waves (4m x 2n)
__global__ __launch_bounds__(512, 1) void conv1_mfma(
    const int* __restrict__ tp, const int* __restrict__ tcu, const int* __restrict__ tn,
    const ushort* __restrict__ ebf, const ushort* __restrict__ w1bf,
    const float* __restrict__ b1, ushort* __restrict__ y1)
{
    constexpr int LDA = 136;
    __shared__ ushort As[258 * LDA];   // t = -1..256 (halo), e 0..127
    __shared__ ushort Bs[128 * LDA];
    __shared__ int tokL[258 * 8];
    const int tid = threadIdx.x;
    const int bx = blockIdx.x;
    const int nb = bx & 3, mb = bx >> 2;       // mb = set*32 + bb
    const int set = mb >> 5, bb = mb & 31;
    const int n0 = nb << 7;
    const int* tok = (set == 0) ? tp : ((set == 1) ? tcu : tn);

    for (int idx = tid; idx < 2064; idx += 512) {
        const int row = idx >> 3, cc = idx & 7;
        const int gt = row - 1;
        tokL[idx] = (gt >= 0 && gt < 256) ? tok[bb * 2048 + gt * 8 + cc] : -1;
    }
    __syncthreads();

    const int w = tid >> 6, lane = tid & 63;
    const int wm = w & 3, wn = w >> 2;         // 4 m-groups x 2 n-groups
    const int rA = lane & 15, q4 = lane >> 4;
    const int ch = tid & 15, rowst = tid >> 4; // 32 rows per staging pass

    floatx4 acc[4][4];                          // [mi][ni]
    for (int mi = 0; mi < 4; ++mi)
        for (int ni = 0; ni < 4; ++ni)
            acc[mi][ni] = (floatx4)(0.0f);

    for (int cc = 0; cc < 8; ++cc) {
        // stage A: 258 t-rows x 128 e (reused by all 3 kw)
        for (int p = 0; p < 9; ++p) {
            const int row = p * 32 + rowst;
            if (row < 258) {
                const int tk = tokL[row * 8 + cc];
                uint4 val = make_uint4(0u, 0u, 0u, 0u);
                if (tk >= 0) val = *(const uint4*)(ebf + tk * 128 + ch * 8);
                *(uint4*)(As + row * LDA + ch * 8) = val;
            }
        }
        for (int kw = 0; kw < 3; ++kw) {
            const ushort* wsrc = w1bf + ((size_t)((kw * 8 + cc) * 512 + n0)) * 128;
            for (int p = 0; p < 4; ++p) {
                const int row = p * 32 + rowst;
                *(uint4*)(Bs + row * LDA + ch * 8) = *(const uint4*)(wsrc + row * 128 + ch * 8);
            }
            __syncthreads();
            for (int ks = 0; ks < 4; ++ks) {
                const int k0 = ks * 32 + q4 * 8;
                short8 a[4], bfr[4];
                for (int mi = 0; mi < 4; ++mi)
                    a[mi] = *(const short8*)(As + (wm * 64 + mi * 16 + rA + kw) * LDA + k0);
                for (int ni = 0; ni < 4; ++ni)
                    bfr[ni] = *(const short8*)(Bs + (wn * 64 + ni * 16 + rA) * LDA + k0);
                for (int mi = 0; mi < 4; ++mi)
                    for (int ni = 0; ni < 4; ++ni)
                        acc[mi][ni] = __builtin_amdgcn_mfma_f32_16x16x32_bf16(
                            a[mi], bfr[ni], acc[mi][ni], 0, 0, 0);
            }
            __syncthreads();
        }
    }
    for (int ni = 0; ni < 4; ++ni) {
        const int co = n0 + wn * 64 + ni * 16 + rA;
        const float bias = b1[co];
        for (int mi = 0; mi < 4; ++mi) {
            for (int r = 0; r < 4; ++r) {
                const int t = wm * 64 + mi * 16 + q4 * 4 + r;
                float v = acc[mi][ni][r] + bias;
                v = v > 0.f ? v : 0.f;
                y1[((size_t)(set * 32 + bb) * 256 + t) * 512 + co] = f2bf(v);
            }
        }
    }
}

// ---------------- conv2 + avgpool(64): 128x128 tile ----------------
__global__ __launch_bounds__(512, 4) void conv2_mfma(
    const ushort* __restrict__ y1, const ushort* __restrict__ w2bf,
    const float* __restrict__ b2, float* __restrict__ y2)
{
    constexpr int LDA = 136;
    __shared__ ushort As[128 * LDA];
    __shared__ ushort Bs[128 * LDA];
    __shared__ float pool[256];
    const int tid = threadIdx.x;
    const int bx = blockIdx.x;
    const int nb = bx & 1, mb = bx >> 1;
    const int set = mb >> 6, rem = mb & 63, bb = rem >> 1, t0 = (rem & 1) << 7;
    const int n0 = nb << 7;
    const int w = tid >> 6, lane = tid & 63;
    const int wm = w & 1, wn = w >> 1;
    const int rA = lane & 15, q4 = lane >> 4;
    const int ch = tid & 15, rowst = tid >> 4;

    floatx4 acc[4][2];
    for (int mi = 0; mi < 4; ++mi)
        for (int ni = 0; ni < 2; ++ni)
            acc[mi][ni] = (floatx4)(0.0f);

    const size_t arowbase = ((size_t)(set * 32 + bb) * 256 + t0) * 512;
    for (int kc = 0; kc < 4; ++kc) {
        for (int p = 0; p < 4; ++p) {
            const int row = p * 32 + rowst;
            *(uint4*)(As + row * LDA + ch * 8) =
                *(const uint4*)(y1 + arowbase + (size_t)row * 512 + kc * 128 + ch * 8);
            *(uint4*)(Bs + row * LDA + ch * 8) =
                *(const uint4*)(w2bf + (size_t)(n0 + row) * 512 + kc * 128 + ch * 8);
        }
        __syncthreads();
        for (int ks = 0; ks < 4; ++ks) {
            const int k0 = ks * 32 + q4 * 8;
            short8 a[4], bfr[2];
            for (int mi = 0; mi < 4; ++mi)
                a[mi] = *(const short8*)(As + (wm * 64 + mi * 16 + rA) * LDA + k0);
            for (int ni = 0; ni < 2; ++ni)
                bfr[ni] = *(const short8*)(Bs + (wn * 32 + ni * 16 + rA) * LDA + k0);
            for (int mi = 0; mi < 4; ++mi)
                for (int ni = 0; ni < 2; ++ni)
                    acc[mi][ni] = __builtin_amdgcn_mfma_f32_16x16x32_bf16(
                        a[mi], bfr[ni], acc[mi][ni], 0, 0, 0);
        }
        __syncthreads();
    }
    for (int ni = 0; ni < 2; ++ni) {
        const int col = wn * 32 + ni * 16 + rA;
        const float bias = b2[n0 + col];
        float s = 0.f;
        for (int mi = 0; mi < 4; ++mi)
            for (int r = 0; r < 4; ++r) {
                float v = acc[mi][ni][r] + bias;
                s += v > 0.f ? v : 0.f;
            }
        s += __shfl_xor(s, 16);
        s += __shfl_xor(s, 32);
        if (q4 == 0) pool[wm * 128 + col] = s;
    }
    __syncthreads();
    if (tid < 256) {
        const int wrow = tid >> 7, col = tid & 127;
        const int p = (t0 >> 6) + wrow;
        y2[((size_t)(set * 32 + bb) * 4 + p) * 256 + n0 + col] = pool[tid] * (1.f / 64.f);
    }
}

// ---------------- VQ ----------------
__global__ __launch_bounds__(256) void vq_kernel(
    const float* __restrict__ y2, const float* __restrict__ cbiT, const float* __restrict__ cbvT,
    const float* __restrict__ cbi, const float* __restrict__ cbv,
    const float* __restrict__ pos, float* __restrict__ ztr, float* __restrict__ accum)
{
    const int q = blockIdx.x;
    const int tid = threadIdx.x;
    const int set = q >> 7, bb = (q >> 2) & 31, p = q & 3;
    __shared__ float zloc[256];
    __shared__ float bestv[4];
    __shared__ int   besti[4];
    __shared__ int   code_sh[2];
    __shared__ float wsum2[4];
    zloc[tid] = y2[(size_t)q * 256 + tid];
    __syncthreads();
    const int w = tid >> 6, lane = tid & 63;
    const int half = w >> 1, sub = w & 1;
    const float4* cbT4 = (const float4*)(half ? cbvT : cbiT);
    const float* zh = zloc + half * 128;
    const int k4 = sub * 64 + lane;
    float a0 = 0.f, a1 = 0.f, a2 = 0.f, a3 = 0.f;
    for (int d = 0; d < 128; ++d) {
        float4 v = cbT4[d * 128 + k4];
        const float z = zh[d];
        float d0 = z - v.x, d1 = z - v.y, d2 = z - v.z, d3 = z - v.w;
        a0 += d0 * d0; a1 += d1 * d1; a2 += d2 * d2; a3 += d3 * d3;
    }
    float best = a0; int bidx = k4 * 4;
    if (a1 < best) { best = a1; bidx = k4 * 4 + 1; }
    if (a2 < best) { best = a2; bidx = k4 * 4 + 2; }
    if (a3 < best) { best = a3; bidx = k4 * 4 + 3; }
    for (int off = 32; off > 0; off >>= 1) {
        float ov = __shfl_xor(best, off);
        int   oi = __shfl_xor(bidx, off);
        if (ov < best || (ov == best && oi < bidx)) { best = ov; bidx = oi; }
    }
    if (lane == 0) { bestv[w] = best; besti[w] = bidx; }
    __syncthreads();
    if (tid < 2) {
        float v0 = bestv[tid * 2], v1 = bestv[tid * 2 + 1];
        int   i0 = besti[tid * 2], i1 = besti[tid * 2 + 1];
        code_sh[tid] = (v1 < v0 || (v1 == v0 && i1 < i0)) ? i1 : i0;
    }
    __syncthreads();
    const int hh = tid >> 7, d = tid & 127;
    const int code = code_sh[hh];
    const float* cb = hh ? cbv : cbi;
    const float zq = cb[code * 128 + d];
    const float diff = zloc[hh * 128 + d] - zq;
    float sq = diff * diff;
    for (int off = 32; off > 0; off >>= 1) sq += __shfl_xor(sq, off);
    if (lane == 0) wsum2[w] = sq;
    const int s = (set * 2 + hh) * 4 + p;
    ztr[((size_t)bb * 24 + s) * 128 + d] = zq + pos[s * 128 + d];
    __syncthreads();
    if (tid == 0) atomicAdd(&accum[0], wsum2[0] + wsum2[1] + wsum2[2] + wsum2[3]);
}

// ---------------- fused transformer tail: one block per batch ----------------
__global__ __launch_bounds__(256) void tail_kernel(
    const float* __restrict__ ztr,
    const ushort* __restrict__ aiwbf, const float* __restrict__ aib,
    const ushort* __restrict__ aowbf, const float* __restrict__ aob,
    const float* __restrict__ g1, const float* __restrict__ be1,
    const ushort* __restrict__ l1wbf, const float* __restrict__ l1b,
    const ushort* __restrict__ l2wbf, const float* __restrict__ l2b,
    const float* __restrict__ g2, const float* __restrict__ be2,
    const float* __restrict__ lora_a, float* __restrict__ hbuf)
{
    __shared__ __align__(16) char LDSC[162304];
    float*  Xf  = (float*)LDSC;
    ushort* Abf = (ushort*)(LDSC + 12288);
    char*   S   = LDSC + 20992;
    ushort* Wq  = (ushort*)S;
    float*  QKV = (float*)(S + 104448);
    float*  Ssc = (float*)S;
    ushort* Wo  = (ushort*)S;
    ushort* W1  = (ushort*)S;
    ushort* Hbf = (ushort*)S;
    ushort* Wh  = (ushort*)(S + 34304);
    float*  ps  = (float*)(S + 104448);
    float*  pq  = (float*)(S + 104960);
    float*  muv = (float*)(S + 105472);
    float*  inv = (float*)(S + 105600);

    const int b = blockIdx.x;
    const int tid = threadIdx.x;
    const int w = tid >> 6, lane = tid & 63;
    const int rA = lane & 15, q4 = lane >> 4;

    for (int i = tid; i < 544; i += 256) ((uint4*)Abf)[i] = make_uint4(0u, 0u, 0u, 0u);
    __syncthreads();
    for (int i = tid; i < 3072; i += 256) {
        float v = ztr[(size_t)b * 3072 + i];
        Xf[i] = v;
        Abf[(i >> 7) * 136 + (i & 127)] = f2bf(v);
    }
    for (int i = tid; i < 6144; i += 256) {
        const int row = i >> 4, ch = i & 15;
        *(uint4*)(Wq + row * 136 + ch * 8) = *(const uint4*)(aiwbf + row * 128 + ch * 8);
    }
    __syncthreads();

    {
        floatx4 acc[2][6];
        for (int mi = 0; mi < 2; ++mi) for (int ni = 0; ni < 6; ++ni) acc[mi][ni] = (floatx4)(0.f);
        for (int ks = 0; ks < 4; ++ks) {
            const int k0 = ks * 32 + q4 * 8;
            short8 a[2];
            for (int mi = 0; mi < 2; ++mi)
                a[mi] = *(const short8*)(Abf + (mi * 16 + rA) * 136 + k0);
            for (int ni = 0; ni < 6; ++ni) {
                short8 bfr = *(const short8*)(Wq + ((w * 6 + ni) * 16 + rA) * 136 + k0);
                for (int mi = 0; mi < 2; ++mi)
                    acc[mi][ni] = __builtin_amdgcn_mfma_f32_16x16x32_bf16(a[mi], bfr, acc[mi][ni], 0, 0, 0);
            }
        }
        for (int ni = 0; ni < 6; ++ni) {
            const int col = (w * 6 + ni) * 16 + rA;
            const float bs = aib[col];
            for (int mi = 0; mi < 2; ++mi)
                for (int r = 0; r < 4; ++r) {
                    const int row = mi * 16 + q4 * 4 + r;
                    if (row < 24) QKV[row * 384 + col] = acc[mi][ni][r] + bs;
                }
        }
    }
    __syncthreads();

    {
        const int h = w;
        for (int l = 0; l < 9; ++l) {
            const int e = l * 64 + lane;
            const int i = e / 24, j = e - i * 24;
            float s = 0.f;
            for (int d = 0; d < 32; ++d)
                s += QKV[i * 384 + h * 32 + d] * QKV[j * 384 + 128 + h * 32 + d];
            Ssc[w * 576 + i * 24 + j] = s * 0.17677669529663687f;
        }
        __syncthreads();
        if (lane < 24) {
            float* row = Ssc + w * 576 + lane * 24;
            float m = row[0];
            for (int j = 1; j < 24; ++j) m = row[j] > m ? row[j] : m;
            float ssum = 0.f;
            for (int j = 0; j < 24; ++j) { float e = __expf(row[j] - m); row[j] = e; ssum += e; }
            float iv = 1.f / ssum;
            for (int j = 0; j < 24; ++j) row[j] *= iv;
        }
        __syncthreads();
        for (int l = 0; l < 12; ++l) {
            const int idx = l * 64 + lane;
            const int s = idx >> 5, d = idx & 31;
            float a = 0.f;
            for (int j = 0; j < 24; ++j)
                a += Ssc[w * 576 + s * 24 + j] * QKV[j * 384 + 256 + h * 32 + d];
            Abf[s * 136 + h * 32 + d] = f2bf(a);
        }
    }
    __syncthreads();

    for (int i = tid; i < 2048; i += 256) {
        const int row = i >> 4, ch = i & 15;
        *(uint4*)(Wo + row * 136 + ch * 8) = *(const uint4*)(aowbf + row * 128 + ch * 8);
    }
    __syncthreads();
    {
        floatx4 acc[2][2];
        for (int mi = 0; mi < 2; ++mi) for (int ni = 0; ni < 2; ++ni) acc[mi][ni] = (floatx4)(0.f);
        for (int ks = 0; ks < 4; ++ks) {
            const int k0 = ks * 32 + q4 * 8;
            short8 a[2];
            for (int mi = 0; mi < 2; ++mi)
                a[mi] = *(const short8*)(Abf + (mi * 16 + rA) * 136 + k0);
            for (int ni = 0; ni < 2; ++ni) {
                short8 bfr = *(const short8*)(Wo + ((w * 2 + ni) * 16 + rA) * 136 + k0);
                for (int mi = 0; mi < 2; ++mi)
                    acc[mi][ni] = __builtin_amdgcn_mfma_f32_16x16x32_bf16(a[mi], bfr, acc[mi][ni], 0, 0, 0);
            }
        }
        for (int ni = 0; ni < 2; ++ni) {
            const int col = (w * 2 + ni) * 16 + rA;
            const float bs = aob[col];
            for (int mi = 0; mi < 2; ++mi)
                for (int r = 0; r < 4; ++r) {
                    const int row = mi * 16 + q4 * 4 + r;
                    acc[mi][ni][r] += bs + (row < 24 ? Xf[row * 128 + col] : 0.f);
                }
        }
        for (int mi = 0; mi < 2; ++mi)
            for (int r = 0; r < 4; ++r) {
                float s  = acc[mi][0][r] + acc[mi][1][r];
                float sq = acc[mi][0][r] * acc[mi][0][r] + acc[mi][1][r] * acc[mi][1][r];
                for (int off = 1; off < 16; off <<= 1) { s += __shfl_xor(s, off); sq += __shfl_xor(sq, off); }
                if (rA == 0) { const int rl = mi * 16 + q4 * 4 + r; ps[rl * 4 + w] = s; pq[rl * 4 + w] = sq; }
            }
        __syncthreads();
        if (tid < 32) {
            float s  = ps[tid * 4] + ps[tid * 4 + 1] + ps[tid * 4 + 2] + ps[tid * 4 + 3];
            float sq = pq[tid * 4] + pq[tid * 4 + 1] + pq[tid * 4 + 2] + pq[tid * 4 + 3];
            float mu = s * (1.f / 128.f);
            float var = sq * (1.f / 128.f) - mu * mu;
            muv[tid] = mu; inv[tid] = rsqrtf(var + 1e-5f);
        }
        __syncthreads();
        for (int ni = 0; ni < 2; ++ni) {
            const int col = (w * 2 + ni) * 16 + rA;
            const float gg = g1[col], bb2 = be1[col];
            for (int mi = 0; mi < 2; ++mi)
                for (int r = 0; r < 4; ++r) {
                    const int rl = mi * 16 + q4 * 4 + r;
                    if (rl < 24) {
                        float v = (acc[mi][ni][r] - muv[rl]) * inv[rl] * gg + bb2;
                        Xf[rl * 128 + col] = v;
                        Abf[rl * 136 + col] = f2bf(v);
                    }
                }
        }
    }
    __syncthreads();

    for (int i = tid; i < 8192; i += 256) {
        const int row = i >> 4, ch = i & 15;
        *(uint4*)(W1 + row * 136 + ch * 8) = *(const uint4*)(l1wbf + row * 128 + ch * 8);
    }
    __syncthreads();
    {
        floatx4 acc[2][8];
        for (int mi = 0; mi < 2; ++mi) for (int ni = 0; ni < 8; ++ni) acc[mi][ni] = (floatx4)(0.f);
        for (int ks = 0; ks < 4; ++ks) {
            const int k0 = ks * 32 + q4 * 8;
            short8 a[2];
            for (int mi = 0; mi < 2; ++mi)
                a[mi] = *(const short8*)(Abf + (mi * 16 + rA) * 136 + k0);
            for (int ni = 0; ni < 8; ++ni) {
                short8 bfr = *(const short8*)(W1 + ((w * 8 + ni) * 16 + rA) * 136 + k0);
                for (int mi = 0; mi < 2; ++mi)
                    acc[mi][ni] = __builtin_amdgcn_mfma_f32_16x16x32_bf16(a[mi], bfr, acc[mi][ni], 0, 0, 0);
            }
        }
        __syncthreads();
        for (int i = tid; i < 536; i += 256) ((uint4*)(Hbf + 24 * 536))[i] = make_uint4(0u, 0u, 0u, 0u);
        for (int ni = 0; ni < 8; ++ni) {
            const int col = (w * 8 + ni) * 16 + rA;
            const float bs = l1b[col];
            for (int mi = 0; mi < 2; ++mi)
                for (int r = 0; r < 4; ++r) {
                    const int row = mi * 16 + q4 * 4 + r;
                    if (row < 24) {
                        float v = acc[mi][ni][r] + bs;
                        Hbf[row * 536 + col] = f2bf(v > 0.f ? v : 0.f);
                    }
                }
        }
    }
    __syncthreads();

    {
        floatx4 acc[2][2];
        for (int mi = 0; mi < 2; ++mi) for (int ni = 0; ni < 2; ++ni) acc[mi][ni] = (floatx4)(0.f);
        for (int kh = 0; kh < 2; ++kh) {
            for (int i = tid; i < 4096; i += 256) {
                const int row = i >> 5, ch = i & 31;
                *(uint4*)(Wh + row * 264 + ch * 8) =
                    *(const uint4*)(l2wbf + row * 512 + kh * 256 + ch * 8);
            }
            __syncthreads();
            for (int ks = 0; ks < 8; ++ks) {
                const int k0 = ks * 32 + q4 * 8;
                short8 a[2];
                for (int mi = 0; mi < 2; ++mi)
                    a[mi] = *(const short8*)(Hbf + (mi * 16 + rA) * 536 + kh * 256 + k0);
                for (int ni = 0; ni < 2; ++ni) {
                    short8 bfr = *(const short8*)(Wh + ((w * 2 + ni) * 16 + rA) * 264 + k0);
                    for (int mi = 0; mi < 2; ++mi)
                        acc[mi][ni] = __builtin_amdgcn_mfma_f32_16x16x32_bf16(a[mi], bfr, acc[mi][ni], 0, 0, 0);
                }
            }
            __syncthreads();
        }
        for (int ni = 0; ni < 2; ++ni) {
            const int col = (w * 2 + ni) * 16 + rA;
            const float bs = l2b[col];
            for (int mi = 0; mi < 2; ++mi)
                for (int r = 0; r < 4; ++r) {
                    const int row = mi * 16 + q4 * 4 + r;
                    acc[mi][ni][r] += bs + (row < 24 ? Xf[row * 128 + col] : 0.f);
                }
        }
        for (int mi = 0; mi < 2; ++mi)
            for (int r = 0; r < 4; ++r) {
                float s  = acc[mi][0][r] + acc[mi][1][r];
                float sq = acc[mi][0][r] * acc[mi][0][r] + acc[mi][1][r] * acc[mi][1][r];
                for (int off = 1; off < 16; off <<= 1) { s += __shfl_xor(s, off); sq += __shfl_xor(sq, off); }
                if (rA == 0) { const int rl = mi * 16 + q4 * 4 + r; ps[rl * 4 + w] = s; pq[rl * 4 + w] = sq; }
            }
        __syncthreads();
        if (tid < 32) {
            float s  = ps[tid * 4] + ps[tid * 4 + 1] + ps[tid * 4 + 2] + ps[tid * 4 + 3];
            float sq = pq[tid * 4] + pq[tid * 4 + 1] + pq[tid * 4 + 2] + pq[tid * 4 + 3];
            float mu = s * (1.f / 128.f);
            float var = sq * (1.f / 128.f) - mu * mu;
            muv[tid] = mu; inv[tid] = rsqrtf(var + 1e-5f);
        }
        __syncthreads();
        for (int ni = 0; ni < 2; ++ni) {
            const int col = (w * 2 + ni) * 16 + rA;
            const float gg = g2[col], bb2 = be2[col];
            for (int mi = 0; mi < 2; ++mi)
                for (int r = 0; r < 4; ++r) {
                    const int rl = mi * 16 + q4 * 4 + r;
                    if (rl < 24)
                        Xf[rl * 128 + col] = (acc[mi][ni][r] - muv[rl]) * inv[rl] * gg + bb2;
                }
        }
    }
    __syncthreads();

    for (int rr = 0; rr < 2; ++rr) {
        const int r = w + rr * 4;
        float a = 0.f;
        for (int i = lane; i < 3072; i += 64)
            a += lora_a[(size_t)r * 3072 + i] * Xf[i];
        for (int off = 32; off > 0; off >>= 1) a += __shfl_xor(a, off);
        if (lane == 0) hbuf[b * 8 + r] = a;
    }
}

// ---------------- logits + log-softmax + NLL + fused finalize ----------------
__global__ __launch_bounds__(256) void logits_kernel(
    const float* __restrict__ hbuf, const float* __restrict__ lora_b,
    const int* __restrict__ tokc, float* __restrict__ accum, float* __restrict__ out)
{
    const int tid = threadIdx.x;
    const int tcb = blockIdx.x;
    __shared__ float hl[256];
    __shared__ float wsum[4];
    __shared__ float ltok;
    hl[tid] = hbuf[tid];
    float wr[4][8];
    for (int i = 0; i < 4; ++i) {
        const float4* pw = (const float4*)(lora_b + ((size_t)tcb * 1024 + tid + 256 * i) * 8);
        float4 x = pw[0], y = pw[1];
        wr[i][0] = x.x; wr[i][1] = x.y; wr[i][2] = x.z; wr[i][3] = x.w;
        wr[i][4] = y.x; wr[i][5] = y.y; wr[i][6] = y.z; wr[i][7] = y.w;
    }
    __syncthreads();
    float nll = 0.f;
    for (int bb = 0; bb < 32; ++bb) {
        const int tv = tokc[bb * 2048 + tcb];
        const float* h = hl + bb * 8;
        float h0 = h[0], h1 = h[1], h2 = h[2], h3 = h[3];
        float h4 = h[4], h5 = h[5], h6 = h[6], h7 = h[7];
        float sl = 0.f;
        for (int i = 0; i < 4; ++i) {
            float lg = h0 * wr[i][0] + h1 * wr[i][1] + h2 * wr[i][2] + h3 * wr[i][3]
                     + h4 * wr[i][4] + h5 * wr[i][5] + h6 * wr[i][6] + h7 * wr[i][7];
            sl += __expf(lg);
            if (tid + 256 * i == tv) ltok = lg;
        }
        for (int off = 32; off > 0; off >>= 1) sl += __shfl_xor(sl, off);
        if ((tid & 63) == 0) wsum[tid >> 6] = sl;
        __syncthreads();
        if (tid == 0) nll += logf(wsum[0] + wsum[1] + wsum[2] + wsum[3]) - ltok;
        __syncthreads();
    }
    if (tid == 0) {
        atomicAdd(&accum[1], nll);
        __threadfence();
        unsigned int prev = atomicAdd((unsigned int*)(accum + 2), 1u);
        if (prev == 2047u) {
            float vq  = atomicAdd(&accum[0], 0.f);
            float rec = atomicAdd(&accum[1], 0.f);
            out[0] = rec * (1.f / 65536.f) + 0.05f * vq * (1.f / 16384.f);
        }
    }
}

// ---------------- host ----------------
extern "C" void kernel_launch(void* const* d_in, const int* in_sizes, int n_in,
                              void* d_out, int out_size, void* d_ws, size_t ws_size,
                              hipStream_t stream) {
    const int*   tp   = (const int*)d_in[0];
    const int*   tcu  = (const int*)d_in[1];
    const int*   tn   = (const int*)d_in[2];
    const float* emb  = (const float*)d_in[3];
    const float* w1   = (const float*)d_in[4];
    const float* b1   = (const float*)d_in[5];
    const float* w2   = (const float*)d_in[6];
    const float* b2   = (const float*)d_in[7];
    const float* cbi  = (const float*)d_in[8];
    const float* cbv  = (const float*)d_in[9];
    const float* pos  = (const float*)d_in[10];
    const float* aiw  = (const float*)d_in[11];
    const float* aib  = (const float*)d_in[12];
    const float* aow  = (const float*)d_in[13];
    const float* aob  = (const float*)d_in[14];
    const float* g1   = (const float*)d_in[15];
    const float* be1  = (const float*)d_in[16];
    const float* l1w  = (const float*)d_in[17];
    const float* l1b  = (const float*)d_in[18];
    const float* l2w  = (const float*)d_in[19];
    const float* l2b  = (const float*)d_in[20];
    const float* g2   = (const float*)d_in[21];
    const float* be2  = (const float*)d_in[22];
    const float* lra  = (const float*)d_in[23];
    const float* lrb  = (const float*)d_in[24];

    char* wsb = (char*)d_ws;
    ushort* ebf  = (ushort*)(wsb + 0);            // 262144 B
    ushort* w1bf = (ushort*)(wsb + 262144);       // 3145728 B
    ushort* w2bf = (ushort*)(wsb + 3407872);      // 262144 B
    float*  cbiT = (float*)(wsb + 3670016);       // 262144 B
    float*  cbvT = (float*)(wsb + 3932160);       // 262144 B
    ushort* y1   = (ushort*)(wsb + 4194304);      // 25165824 B
    float*  y2   = (float*)(wsb + 29360128);      // 393216 B
    float*  ztr  = (float*)(wsb + 29753344);      // 393216 B
    float*  hbuf = (float*)(wsb + 30146560);      // 1024 B
    float*  accum= (float*)(wsb + 30147584);      // 64 B
    ushort* aiwbf= (ushort*)(wsb + 30147648);     // 98304 B
    ushort* aowbf= (ushort*)(wsb + 30245952);     // 32768 B
    ushort* l1wbf= (ushort*)(wsb + 30278720);     // 131072 B
    ushort* l2wbf= (ushort*)(wsb + 30409792);     // 131072 B -> 30540864
    if (ws_size < 30540864) return;

    prep_all<<<4416, 256, 0, stream>>>(emb, w1, w2, cbi, cbv, aiw, aow, l1w, l2w,
                                       ebf, w1bf, w2bf, cbiT, cbvT,
                                       aiwbf, aowbf, l1wbf, l2wbf, accum);
    conv1_mfma<<<384, 512, 0, stream>>>(tp, tcu, tn, ebf, w1bf, b1, y1);
    conv2_mfma<<<384, 512, 0, stream>>>(y1, w2bf, b2, y2);
    vq_kernel<<<384, 256, 0, stream>>>(y2, cbiT, cbvT, cbi, cbv, pos, ztr, accum);
    tail_kernel<<<32, 256, 0, stream>>>(ztr, aiwbf, aib, aowbf, aob, g1, be1,
                                        l1wbf, l1b, l2wbf, l2b, g2, be2, lra, hbuf);
    logits_kernel<<<2048, 256, 0, stream>>>(hbuf, lrb, tcu, accum, (float*)d_out);
}

// Round 8
// 360.978 us; speedup vs baseline: 1.3434x; 1.1901x over previous
//
#include <hip/hip_runtime.h>
#include <hip/hip_bf16.h>
#include <cstdint>
#include <cstddef>

typedef __attribute__((ext_vector_type(8))) short short8;
typedef __attribute__((ext_vector_type(4))) float floatx4;

// V=1024 C=8 T=256 BP=4 K=512 E=128 D=128 NB=24 NH=4 HD=32 FF=512 R=8 B=32

__device__ __forceinline__ ushort f2bf(float f) {
    union { float f; unsigned int u; } x; x.f = f;
    unsigned int r = (x.u + 0x7fffu + ((x.u >> 16) & 1u)) >> 16;
    return (ushort)r;
}
__device__ __forceinline__ float bf2f(ushort u) {
    union { unsigned int u; float f; } x; x.u = ((unsigned int)u) << 16;
    return x.f;
}

// ---------------- single merged prep kernel ----------------
__global__ __launch_bounds__(256) void prep_all(
    const float* __restrict__ emb, const float* __restrict__ w1,
    const float* __restrict__ w2, const float* __restrict__ cbi,
    const float* __restrict__ cbv, const float* __restrict__ aiw,
    const float* __restrict__ aow, const float* __restrict__ l1w,
    const float* __restrict__ l2w,
    ushort* __restrict__ ebf, ushort* __restrict__ w1bf, ushort* __restrict__ w2bf,
    float* __restrict__ cbiT, float* __restrict__ cbvT,
    ushort* __restrict__ aiwbf, ushort* __restrict__ aowbf,
    ushort* __restrict__ l1wbf, ushort* __restrict__ l2wbf,
    float* __restrict__ accum)
{
    int idx = blockIdx.x * 256 + threadIdx.x;
    if (idx < 16) accum[idx] = 0.f;
    if (idx < 131072) {
        ebf[idx] = f2bf(emb[idx]);
    } else if (idx < 262144) {
        int j = idx - 131072; w2bf[j] = f2bf(w2[j]);
    } else if (idx < 327680) {
        int j = idx - 262144; cbiT[(j & 127) * 512 + (j >> 7)] = cbi[j];
    } else if (idx < 393216) {
        int j = idx - 327680; cbvT[(j & 127) * 512 + (j >> 7)] = cbv[j];
    } else if (idx < 442368) {
        int j = idx - 393216; aiwbf[j] = f2bf(aiw[j]);
    } else if (idx < 475136) {
        int j = idx - 442368; aowbf[j] = f2bf(aow[j]);
    } else if (idx < 540672) {
        int j = idx - 475136; l1wbf[j] = f2bf(l1w[j]);
    } else if (idx < 606208) {
        int j = idx - 540672; l2wbf[j] = f2bf(l2w[j]);
    } else if (idx < 1130496) {
        int j = idx - 606208;            // (co*8+cc)*128+e, all 3 kw per thread
        int e  = j & 127;
        int cc = (j >> 7) & 7;
        int co = j >> 10;
        const float* src = w1 + ((size_t)co * 1024 + cc * 128 + e) * 3;
        float v0 = src[0], v1 = src[1], v2 = src[2];
        w1bf[((size_t)(0 * 8 + cc) * 512 + co) * 128 + e] = f2bf(v0);
        w1bf[((size_t)(1 * 8 + cc) * 512 + co) * 128 + e] = f2bf(v1);
        w1bf[((size_t)(2 * 8 + cc) * 512 + co) * 128 + e] = f2bf(v2);
    }
}

// ---------------- conv1: implicit GEMM, 128x128 tile, A-halo reuse over kw (R3 best) ----------------
__global__ __launch_bounds__(512, 4) void conv1_mfma(
    const int* __restrict__ tp, const int* __restrict__ tcu, const int* __restrict__ tn,
    const ushort* __restrict__ ebf, const ushort* __restrict__ w1bf,
    const float* __restrict__ b1, ushort* __restrict__ y1)
{
    constexpr int LDA = 136;
    __shared__ ushort As[130 * LDA];
    __shared__ ushort Bs[128 * LDA];
    __shared__ int tokL[130 * 8];
    const int tid = threadIdx.x;
    const int bx = blockIdx.x;
    const int nb = bx & 3, mb = bx >> 2;
    const int set = mb >> 6, rem = mb & 63, bb = rem >> 1, t0 = (rem & 1) << 7;
    const int n0 = nb << 7;
    const int* tok = (set == 0) ? tp : ((set == 1) ? tcu : tn);

    for (int idx = tid; idx < 1040; idx += 512) {
        const int row = idx >> 3, cc = idx & 7;
        const int gt = t0 + row - 1;
        tokL[idx] = (gt >= 0 && gt < 256) ? tok[bb * 2048 + gt * 8 + cc] : -1;
    }

    const int w = tid >> 6, lane = tid & 63;
    const int wm = w & 1, wn = w >> 1;
    const int rA = lane & 15, q4 = lane >> 4;
    const int ch = tid & 15, rowst = tid >> 4;

    floatx4 acc[4][2];
    for (int mi = 0; mi < 4; ++mi)
        for (int ni = 0; ni < 2; ++ni)
            acc[mi][ni] = (floatx4)(0.0f);

    __syncthreads();

    for (int cc = 0; cc < 8; ++cc) {
        for (int p = 0; p < 5; ++p) {
            const int row = p * 32 + rowst;
            if (row < 130) {
                const int tk = tokL[row * 8 + cc];
                uint4 val = make_uint4(0u, 0u, 0u, 0u);
                if (tk >= 0) val = *(const uint4*)(ebf + tk * 128 + ch * 8);
                *(uint4*)(As + row * LDA + ch * 8) = val;
            }
        }
        for (int kw = 0; kw < 3; ++kw) {
            const ushort* wsrc = w1bf + ((size_t)((kw * 8 + cc) * 512 + n0)) * 128;
            for (int p = 0; p < 4; ++p) {
                const int row = p * 32 + rowst;
                *(uint4*)(Bs + row * LDA + ch * 8) = *(const uint4*)(wsrc + row * 128 + ch * 8);
            }
            __syncthreads();
            for (int ks = 0; ks < 4; ++ks) {
                const int k0 = ks * 32 + q4 * 8;
                short8 a[4], bfr[2];
                for (int mi = 0; mi < 4; ++mi)
                    a[mi] = *(const short8*)(As + (wm * 64 + mi * 16 + rA + kw) * LDA + k0);
                for (int ni = 0; ni < 2; ++ni)
                    bfr[ni] = *(const short8*)(Bs + (wn * 32 + ni * 16 + rA) * LDA + k0);
                for (int mi = 0; mi < 4; ++mi)
                    for (int ni = 0; ni < 2; ++ni)
                        acc[mi][ni] = __builtin_amdgcn_mfma_f32_16x16x32_bf16(
                            a[mi], bfr[ni], acc[mi][ni], 0, 0, 0);
            }
            __syncthreads();
        }
    }
    for (int ni = 0; ni < 2; ++ni) {
        const int co = n0 + wn * 32 + ni * 16 + rA;
        const float bias = b1[co];
        for (int mi = 0; mi < 4; ++mi) {
            for (int r = 0; r < 4; ++r) {
                const int t = t0 + wm * 64 + mi * 16 + q4 * 4 + r;
                float v = acc[mi][ni][r] + bias;
                v = v > 0.f ? v : 0.f;
                y1[((size_t)(set * 32 + bb) * 256 + t) * 512 + co] = f2bf(v);
            }
        }
    }
}

// ---------------- conv2 + avgpool(64): 128x128 tile ----------------
__global__ __launch_bounds__(512, 4) void conv2_mfma(
    const ushort* __restrict__ y1, const ushort* __restrict__ w2bf,
    const float* __restrict__ b2, float* __restrict__ y2)
{
    constexpr int LDA = 136;
    __shared__ ushort As[128 * LDA];
    __shared__ ushort Bs[128 * LDA];
    __shared__ float pool[256];
    const int tid = threadIdx.x;
    const int bx = blockIdx.x;
    const int nb = bx & 1, mb = bx >> 1;
    const int set = mb >> 6, rem = mb & 63, bb = rem >> 1, t0 = (rem & 1) << 7;
    const int n0 = nb << 7;
    const int w = tid >> 6, lane = tid & 63;
    const int wm = w & 1, wn = w >> 1;
    const int rA = lane & 15, q4 = lane >> 4;
    const int ch = tid & 15, rowst = tid >> 4;

    floatx4 acc[4][2];
    for (int mi = 0; mi < 4; ++mi)
        for (int ni = 0; ni < 2; ++ni)
            acc[mi][ni] = (floatx4)(0.0f);

    const size_t arowbase = ((size_t)(set * 32 + bb) * 256 + t0) * 512;
    for (int kc = 0; kc < 4; ++kc) {
        for (int p = 0; p < 4; ++p) {
            const int row = p * 32 + rowst;
            *(uint4*)(As + row * LDA + ch * 8) =
                *(const uint4*)(y1 + arowbase + (size_t)row * 512 + kc * 128 + ch * 8);
            *(uint4*)(Bs + row * LDA + ch * 8) =
                *(const uint4*)(w2bf + (size_t)(n0 + row) * 512 + kc * 128 + ch * 8);
        }
        __syncthreads();
        for (int ks = 0; ks < 4; ++ks) {
            const int k0 = ks * 32 + q4 * 8;
            short8 a[4], bfr[2];
            for (int mi = 0; mi < 4; ++mi)
                a[mi] = *(const short8*)(As + (wm * 64 + mi * 16 + rA) * LDA + k0);
            for (int ni = 0; ni < 2; ++ni)
                bfr[ni] = *(const short8*)(Bs + (wn * 32 + ni * 16 + rA) * LDA + k0);
            for (int mi = 0; mi < 4; ++mi)
                for (int ni = 0; ni < 2; ++ni)
                    acc[mi][ni] = __builtin_amdgcn_mfma_f32_16x16x32_bf16(
                        a[mi], bfr[ni], acc[mi][ni], 0, 0, 0);
        }
        __syncthreads();
    }
    for (int ni = 0; ni < 2; ++ni) {
        const int col = wn * 32 + ni * 16 + rA;
        const float bias = b2[n0 + col];
        float s = 0.f;
        for (int mi = 0; mi < 4; ++mi)
            for (int r = 0; r < 4; ++r) {
                float v = acc[mi][ni][r] + bias;
                s += v > 0.f ? v : 0.f;
            }
        s += __shfl_xor(s, 16);
        s += __shfl_xor(s, 32);
        if (q4 == 0) pool[wm * 128 + col] = s;
    }
    __syncthreads();
    if (tid < 256) {
        const int wrow = tid >> 7, col = tid & 127;
        const int p = (t0 >> 6) + wrow;
        y2[((size_t)(set * 32 + bb) * 4 + p) * 256 + n0 + col] = pool[tid] * (1.f / 64.f);
    }
}

// ---------------- VQ ----------------
__global__ __launch_bounds__(256) void vq_kernel(
    const float* __restrict__ y2, const float* __restrict__ cbiT, const float* __restrict__ cbvT,
    const float* __restrict__ cbi, const float* __restrict__ cbv,
    const float* __restrict__ pos, float* __restrict__ ztr, float* __restrict__ accum)
{
    const int q = blockIdx.x;
    const int tid = threadIdx.x;
    const int set = q >> 7, bb = (q >> 2) & 31, p = q & 3;
    __shared__ float zloc[256];
    __shared__ float bestv[4];
    __shared__ int   besti[4];
    __shared__ int   code_sh[2];
    __shared__ float wsum2[4];
    zloc[tid] = y2[(size_t)q * 256 + tid];
    __syncthreads();
    const int w = tid >> 6, lane = tid & 63;
    const int half = w >> 1, sub = w & 1;
    const float4* cbT4 = (const float4*)(half ? cbvT : cbiT);
    const float* zh = zloc + half * 128;
    const int k4 = sub * 64 + lane;
    float a0 = 0.f, a1 = 0.f, a2 = 0.f, a3 = 0.f;
    for (int d = 0; d < 128; ++d) {
        float4 v = cbT4[d * 128 + k4];
        const float z = zh[d];
        float d0 = z - v.x, d1 = z - v.y, d2 = z - v.z, d3 = z - v.w;
        a0 += d0 * d0; a1 += d1 * d1; a2 += d2 * d2; a3 += d3 * d3;
    }
    float best = a0; int bidx = k4 * 4;
    if (a1 < best) { best = a1; bidx = k4 * 4 + 1; }
    if (a2 < best) { best = a2; bidx = k4 * 4 + 2; }
    if (a3 < best) { best = a3; bidx = k4 * 4 + 3; }
    for (int off = 32; off > 0; off >>= 1) {
        float ov = __shfl_xor(best, off);
        int   oi = __shfl_xor(bidx, off);
        if (ov < best || (ov == best && oi < bidx)) { best = ov; bidx = oi; }
    }
    if (lane == 0) { bestv[w] = best; besti[w] = bidx; }
    __syncthreads();
    if (tid < 2) {
        float v0 = bestv[tid * 2], v1 = bestv[tid * 2 + 1];
        int   i0 = besti[tid * 2], i1 = besti[tid * 2 + 1];
        code_sh[tid] = (v1 < v0 || (v1 == v0 && i1 < i0)) ? i1 : i0;
    }
    __syncthreads();
    const int hh = tid >> 7, d = tid & 127;
    const int code = code_sh[hh];
    const float* cb = hh ? cbv : cbi;
    const float zq = cb[code * 128 + d];
    const float diff = zloc[hh * 128 + d] - zq;
    float sq = diff * diff;
    for (int off = 32; off > 0; off >>= 1) sq += __shfl_xor(sq, off);
    if (lane == 0) wsum2[w] = sq;
    const int s = (set * 2 + hh) * 4 + p;
    ztr[((size_t)bb * 24 + s) * 128 + d] = zq + pos[s * 128 + d];
    __syncthreads();
    if (tid == 0) atomicAdd(&accum[0], wsum2[0] + wsum2[1] + wsum2[2] + wsum2[3]);
}

// ---------------- fused transformer tail: 1024 threads (16 waves) per batch-block ----------------
__global__ __launch_bounds__(1024) void tail_kernel(
    const float* __restrict__ ztr,
    const ushort* __restrict__ aiwbf, const float* __restrict__ aib,
    const ushort* __restrict__ aowbf, const float* __restrict__ aob,
    const float* __restrict__ g1, const float* __restrict__ be1,
    const ushort* __restrict__ l1wbf, const float* __restrict__ l1b,
    const ushort* __restrict__ l2wbf, const float* __restrict__ l2b,
    const float* __restrict__ g2, const float* __restrict__ be2,
    const float* __restrict__ lora_a, float* __restrict__ hbuf)
{
    __shared__ __align__(16) char LDSC[162304];
    float*  Xf  = (float*)LDSC;                    // [24][128] f32 state
    ushort* Abf = (ushort*)(LDSC + 12288);         // [32][136] bf16 A operand
    char*   S   = LDSC + 20992;
    ushort* Wq  = (ushort*)S;                      // 384x136
    float*  QKV = (float*)(S + 104448);            // 24x384
    float*  Ssc = (float*)S;                       // 4x576
    ushort* Wo  = (ushort*)S;                      // 128x136
    float*  psA = (float*)(S + 36864);
    float*  pqA = (float*)(S + 37888);
    float*  muvA= (float*)(S + 38912);
    float*  invA= (float*)(S + 39040);
    ushort* W1  = (ushort*)S;                      // 512x136
    ushort* Hbf = (ushort*)S;                      // 32x520 (stride 520)
    ushort* Wh  = (ushort*)(S + 33280);            // 128x264
    float*  psB = (float*)(S + 100864);
    float*  pqB = (float*)(S + 101888);
    float*  muvB= (float*)(S + 102912);
    float*  invB= (float*)(S + 103040);
    float*  psL = (float*)(S + 103168);

    const int b = blockIdx.x;
    const int tid = threadIdx.x;
    const int w = tid >> 6, lane = tid & 63;
    const int rA = lane & 15, q4 = lane >> 4;
    const int ch = tid & 15;

    // ---- P0: zero Abf, load X, stage Wq ----
    if (tid < 544) ((uint4*)Abf)[tid] = make_uint4(0u, 0u, 0u, 0u);
    __syncthreads();
    for (int i = tid; i < 3072; i += 1024) {
        float v = ztr[(size_t)b * 3072 + i];
        Xf[i] = v;
        Abf[(i >> 7) * 136 + (i & 127)] = f2bf(v);
    }
    for (int i = tid; i < 6144; i += 1024) {
        const int row = i >> 4, c = i & 15;
        *(uint4*)(Wq + row * 136 + c * 8) = *(const uint4*)(aiwbf + row * 128 + c * 8);
    }
    __syncthreads();

    // ---- P1: qkv GEMM (2m x 24n tiles, 3 per wave) ----
    {
        floatx4 acc[3];
        int mI[3], nI[3];
        for (int i = 0; i < 3; ++i) {
            const int t = w + 16 * i;
            mI[i] = t / 24; nI[i] = t % 24;
            acc[i] = (floatx4)(0.f);
        }
        for (int ks = 0; ks < 4; ++ks) {
            const int k0 = ks * 32 + q4 * 8;
            for (int i = 0; i < 3; ++i) {
                short8 a = *(const short8*)(Abf + (mI[i] * 16 + rA) * 136 + k0);
                short8 bf = *(const short8*)(Wq + (nI[i] * 16 + rA) * 136 + k0);
                acc[i] = __builtin_amdgcn_mfma_f32_16x16x32_bf16(a, bf, acc[i], 0, 0, 0);
            }
        }
        for (int i = 0; i < 3; ++i) {
            const int col = nI[i] * 16 + rA;
            const float bs = aib[col];
            for (int r = 0; r < 4; ++r) {
                const int row = mI[i] * 16 + q4 * 4 + r;
                if (row < 24) QKV[row * 384 + col] = acc[i][r] + bs;
            }
        }
    }
    __syncthreads();

    // ---- P2: attention ----
    for (int it = 0; it < 3; ++it) {
        const int e = it * 1024 + tid;
        if (e < 2304) {
            const int h = e / 576, rem = e % 576, i = rem / 24, j = rem % 24;
            float s = 0.f;
            for (int d = 0; d < 32; ++d)
                s += QKV[i * 384 + h * 32 + d] * QKV[j * 384 + 128 + h * 32 + d];
            Ssc[h * 576 + i * 24 + j] = s * 0.17677669529663687f;
        }
    }
    __syncthreads();
    if (tid < 96) {
        const int h = tid / 24, r = tid % 24;
        float* row = Ssc + h * 576 + r * 24;
        float m = row[0];
        for (int j = 1; j < 24; ++j) m = row[j] > m ? row[j] : m;
        float ssum = 0.f;
        for (int j = 0; j < 24; ++j) { float e = __expf(row[j] - m); row[j] = e; ssum += e; }
        float iv = 1.f / ssum;
        for (int j = 0; j < 24; ++j) row[j] *= iv;
    }
    __syncthreads();
    for (int it = 0; it < 3; ++it) {
        const int idx = it * 1024 + tid;
        const int s = idx >> 7, dcol = idx & 127, h = dcol >> 5, d = dcol & 31;
        if (s < 24) {
            float a = 0.f;
            for (int j = 0; j < 24; ++j)
                a += Ssc[h * 576 + s * 24 + j] * QKV[j * 384 + 256 + h * 32 + d];
            Abf[s * 136 + dcol] = f2bf(a);
        }
    }
    __syncthreads();

    // ---- P3: stage Wo ----
    for (int i = tid; i < 2048; i += 1024) {
        const int row = i >> 4, c = i & 15;
        *(uint4*)(Wo + row * 136 + c * 8) = *(const uint4*)(aowbf + row * 128 + c * 8);
    }
    __syncthreads();

    // ---- P4: proj (1 tile/wave) + resid + LN1 ----
    {
        const int m = w & 1, n = w >> 1;
        floatx4 acc = (floatx4)(0.f);
        for (int ks = 0; ks < 4; ++ks) {
            const int k0 = ks * 32 + q4 * 8;
            short8 a = *(const short8*)(Abf + (m * 16 + rA) * 136 + k0);
            short8 bf = *(const short8*)(Wo + (n * 16 + rA) * 136 + k0);
            acc = __builtin_amdgcn_mfma_f32_16x16x32_bf16(a, bf, acc, 0, 0, 0);
        }
        const int col = n * 16 + rA;
        const float bs = aob[col];
        for (int r = 0; r < 4; ++r) {
            const int row = m * 16 + q4 * 4 + r;
            acc[r] += bs + (row < 24 ? Xf[row * 128 + col] : 0.f);
        }
        float s4 = 0.f, q4s = 0.f;
        for (int r = 0; r < 4; ++r) {
            float s = acc[r], sq = acc[r] * acc[r];
            for (int off = 1; off < 16; off <<= 1) { s += __shfl_xor(s, off); sq += __shfl_xor(sq, off); }
            if (rA == 0) {
                const int rl = m * 16 + q4 * 4 + r;
                psA[rl * 8 + n] = s; pqA[rl * 8 + n] = sq;
            }
        }
        (void)s4; (void)q4s;
        __syncthreads();
        if (tid < 32) {
            float s = 0.f, sq = 0.f;
            for (int j = 0; j < 8; ++j) { s += psA[tid * 8 + j]; sq += pqA[tid * 8 + j]; }
            float mu = s * (1.f / 128.f);
            float var = sq * (1.f / 128.f) - mu * mu;
            muvA[tid] = mu; invA[tid] = rsqrtf(var + 1e-5f);
        }
        __syncthreads();
        const float gg = g1[col], bb2 = be1[col];
        for (int r = 0; r < 4; ++r) {
            const int rl = m * 16 + q4 * 4 + r;
            if (rl < 24) {
                float v = (acc[r] - muvA[rl]) * invA[rl] * gg + bb2;
                Xf[rl * 128 + col] = v;
                Abf[rl * 136 + col] = f2bf(v);
            }
        }
    }
    __syncthreads();

    // ---- P5: stage W1 ----
    for (int i = tid; i < 8192; i += 1024) {
        const int row = i >> 4, c = i & 15;
        *(uint4*)(W1 + row * 136 + c * 8) = *(const uint4*)(l1wbf + row * 128 + c * 8);
    }
    __syncthreads();

    // ---- P6: ff1 (4 tiles/wave: fixed m, 4 n's) + relu -> Hbf ----
    {
        const int m = w & 1, n0b = w >> 1;
        floatx4 acc[4];
        for (int i = 0; i < 4; ++i) acc[i] = (floatx4)(0.f);
        for (int ks = 0; ks < 4; ++ks) {
            const int k0 = ks * 32 + q4 * 8;
            short8 a = *(const short8*)(Abf + (m * 16 + rA) * 136 + k0);
            for (int i = 0; i < 4; ++i) {
                const int n = n0b + i * 8;
                short8 bf = *(const short8*)(W1 + (n * 16 + rA) * 136 + k0);
                acc[i] = __builtin_amdgcn_mfma_f32_16x16x32_bf16(a, bf, acc[i], 0, 0, 0);
            }
        }
        __syncthreads();   // W1 reads done; S becomes Hbf
        for (int i = 0; i < 4; ++i) {
            const int col = (n0b + i * 8) * 16 + rA;
            const float bs = l1b[col];
            for (int r = 0; r < 4; ++r) {
                const int row = m * 16 + q4 * 4 + r;
                if (row < 24) {
                    float v = acc[i][r] + bs;
                    Hbf[row * 520 + col] = f2bf(v > 0.f ? v : 0.f);
                }
            }
        }
    }
    __syncthreads();

    // ---- P7: ff2 (K=512 in 2 halves) + resid + LN2 -> Xf ----
    {
        const int m = w & 1, n = w >> 1;
        floatx4 acc = (floatx4)(0.f);
        for (int kh = 0; kh < 2; ++kh) {
            if (kh) __syncthreads();
            for (int i = tid; i < 4096; i += 1024) {
                const int row = i >> 5, c = i & 31;
                *(uint4*)(Wh + row * 264 + c * 8) =
                    *(const uint4*)(l2wbf + row * 512 + kh * 256 + c * 8);
            }
            __syncthreads();
            for (int ks = 0; ks < 8; ++ks) {
                const int k0 = ks * 32 + q4 * 8;
                short8 a = *(const short8*)(Hbf + (m * 16 + rA) * 520 + kh * 256 + k0);
                short8 bf = *(const short8*)(Wh + (n * 16 + rA) * 264 + k0);
                acc = __builtin_amdgcn_mfma_f32_16x16x32_bf16(a, bf, acc, 0, 0, 0);
            }
        }
        const int col = n * 16 + rA;
        const float bs = l2b[col];
        for (int r = 0; r < 4; ++r) {
            const int row = m * 16 + q4 * 4 + r;
            acc[r] += bs + (row < 24 ? Xf[row * 128 + col] : 0.f);
        }
        for (int r = 0; r < 4; ++r) {
            float s = acc[r], sq = acc[r] * acc[r];
            for (int off = 1; off < 16; off <<= 1) { s += __shfl_xor(s, off); sq += __shfl_xor(sq, off); }
            if (rA == 0) {
                const int rl = m * 16 + q4 * 4 + r;
                psB[rl * 8 + n] = s; pqB[rl * 8 + n] = sq;
            }
        }
        __syncthreads();
        if (tid < 32) {
            float s = 0.f, sq = 0.f;
            for (int j = 0; j < 8; ++j) { s += psB[tid * 8 + j]; sq += pqB[tid * 8 + j]; }
            float mu = s * (1.f / 128.f);
            float var = sq * (1.f / 128.f) - mu * mu;
            muvB[tid] = mu; invB[tid] = rsqrtf(var + 1e-5f);
        }
        __syncthreads();
        const float gg = g2[col], bb2 = be2[col];
        for (int r = 0; r < 4; ++r) {
            const int rl = m * 16 + q4 * 4 + r;
            if (rl < 24)
                Xf[rl * 128 + col] = (acc[r] - muvB[rl]) * invB[rl] * gg + bb2;
        }
    }
    __syncthreads();

    // ---- P8: lora_a (wave = (r, seg)) ----
    {
        const int r = w & 7, seg = w >> 3;
        float a = 0.f;
        for (int k = 0; k < 24; ++k) {
            const int idx = seg * 1536 + k * 64 + lane;
            a += lora_a[(size_t)r * 3072 + idx] * Xf[idx];
        }
        for (int off = 32; off > 0; off >>= 1) a += __shfl_xor(a, off);
        if (lane == 0) psL[r * 2 + seg] = a;
        __syncthreads();
        if (tid < 8) hbuf[b * 8 + tid] = psL[tid * 2] + psL[tid * 2 + 1];
    }
}

// ---------------- logits + log-softmax + NLL + fused finalize ----------------
__global__ __launch_bounds__(256) void logits_kernel(
    const float* __restrict__ hbuf, const float* __restrict__ lora_b,
    const int* __restrict__ tokc, float* __restrict__ accum, float* __restrict__ out)
{
    const int tid = threadIdx.x;
    const int tcb = blockIdx.x;
    __shared__ float hl[256];
    __shared__ float wsum[4];
    __shared__ float ltok;
    hl[tid] = hbuf[tid];
    float wr[4][8];
    for (int i = 0; i < 4; ++i) {
        const float4* pw = (const float4*)(lora_b + ((size_t)tcb * 1024 + tid + 256 * i) * 8);
        float4 x = pw[0], y = pw[1];
        wr[i][0] = x.x; wr[i][1] = x.y; wr[i][2] = x.z; wr[i][3] = x.w;
        wr[i][4] = y.x; wr[i][5] = y.y; wr[i][6] = y.z; wr[i][7] = y.w;
    }
    __syncthreads();
    float nll = 0.f;
    for (int bb = 0; bb < 32; ++bb) {
        const int tv = tokc[bb * 2048 + tcb];
        const float* h = hl + bb * 8;
        float h0 = h[0], h1 = h[1], h2 = h[2], h3 = h[3];
        float h4 = h[4], h5 = h[5], h6 = h[6], h7 = h[7];
        float sl = 0.f;
        for (int i = 0; i < 4; ++i) {
            float lg = h0 * wr[i][0] + h1 * wr[i][1] + h2 * wr[i][2] + h3 * wr[i][3]
                     + h4 * wr[i][4] + h5 * wr[i][5] + h6 * wr[i][6] + h7 * wr[i][7];
            sl += __expf(lg);
            if (tid + 256 * i == tv) ltok = lg;
        }
        for (int off = 32; off > 0; off >>= 1) sl += __shfl_xor(sl, off);
        if ((tid & 63) == 0) wsum[tid >> 6] = sl;
        __syncthreads();
        if (tid == 0) nll += logf(wsum[0] + wsum[1] + wsum[2] + wsum[3]) - ltok;
        __syncthreads();
    }
    if (tid == 0) {
        atomicAdd(&accum[1], nll);
        __threadfence();
        unsigned int prev = atomicAdd((unsigned int*)(accum + 2), 1u);
        if (prev == 2047u) {
            float vq  = atomicAdd(&accum[0], 0.f);
            float rec = atomicAdd(&accum[1], 0.f);
            out[0] = rec * (1.f / 65536.f) + 0.05f * vq * (1.f / 16384.f);
        }
    }
}

// ---------------- host ----------------
extern "C" void kernel_launch(void* const* d_in, const int* in_sizes, int n_in,
                              void* d_out, int out_size, void* d_ws, size_t ws_size,
                              hipStream_t stream) {
    const int*   tp   = (const int*)d_in[0];
    const int*   tcu  = (const int*)d_in[1];
    const int*   tn   = (const int*)d_in[2];
    const float* emb  = (const float*)d_in[3];
    const float* w1   = (const float*)d_in[4];
    const float* b1   = (const float*)d_in[5];
    const float* w2   = (const float*)d_in[6];
    const float* b2   = (const float*)d_in[7];
    const float* cbi  = (const float*)d_in[8];
    const float* cbv  = (const float*)d_in[9];
    const float* pos  = (const float*)d_in[10];
    const float* aiw  = (const float*)d_in[11];
    const float* aib  = (const float*)d_in[12];
    const float* aow  = (const float*)d_in[13];
    const float* aob  = (const float*)d_in[14];
    const float* g1   = (const float*)d_in[15];
    const float* be1  = (const float*)d_in[16];
    const float* l1w  = (const float*)d_in[17];
    const float* l1b  = (const float*)d_in[18];
    const float* l2w  = (const float*)d_in[19];
    const float* l2b  = (const float*)d_in[20];
    const float* g2   = (const float*)d_in[21];
    const float* be2  = (const float*)d_in[22];
    const float* lra  = (const float*)d_in[23];
    const float* lrb  = (const float*)d_in[24];

    char* wsb = (char*)d_ws;
    ushort* ebf  = (ushort*)(wsb + 0);            // 262144 B
    ushort* w1bf = (ushort*)(wsb + 262144);       // 3145728 B
    ushort* w2bf = (ushort*)(wsb + 3407872);      // 262144 B
    float*  cbiT = (float*)(wsb + 3670016);       // 262144 B
    float*  cbvT = (float*)(wsb + 3932160);       // 262144 B
    ushort* y1   = (ushort*)(wsb + 4194304);      // 25165824 B
    float*  y2   = (float*)(wsb + 29360128);      // 393216 B
    float*  ztr  = (float*)(wsb + 29753344);      // 393216 B
    float*  hbuf = (float*)(wsb + 30146560);      // 1024 B
    float*  accum= (float*)(wsb + 30147584);      // 64 B
    ushort* aiwbf= (ushort*)(wsb + 30147648);     // 98304 B
    ushort* aowbf= (ushort*)(wsb + 30245952);     // 32768 B
    ushort* l1wbf= (ushort*)(wsb + 30278720);     // 131072 B
    ushort* l2wbf= (ushort*)(wsb + 30409792);     // 131072 B -> 30540864
    if (ws_size < 30540864) return;

    prep_all<<<4416, 256, 0, stream>>>(emb, w1, w2, cbi, cbv, aiw, aow, l1w, l2w,
                                       ebf, w1bf, w2bf, cbiT, cbvT,
                                       aiwbf, aowbf, l1wbf, l2wbf, accum);
    conv1_mfma<<<768, 512, 0, stream>>>(tp, tcu, tn, ebf, w1bf, b1, y1);
    conv2_mfma<<<384, 512, 0, stream>>>(y1, w2bf, b2, y2);
    vq_kernel<<<384, 256, 0, stream>>>(y2, cbiT, cbvT, cbi, cbv, pos, ztr, accum);
    tail_kernel<<<32, 1024, 0, stream>>>(ztr, aiwbf, aib, aowbf, aob, g1, be1,
                                         l1wbf, l1b, l2wbf, l2b, g2, be2, lra, hbuf);
    logits_kernel<<<2048, 256, 0, stream>>>(hbuf, lrb, tcu, accum, (float*)d_out);
}